// Round 7
// baseline (94.056 us; speedup 1.0000x reference)
//
#include <hip/hip_runtime.h>

#define DMD 128
#define NV 64
#define BB 2
#define SQ 512
#define NBN 128                 // BB*NV
#define ASCALE 0.08838834764831845f   // 128^-0.5
#define L2E 1.4426950408889634f
#define CSC (ASCALE * L2E)

// workspace layout (float offsets)
#define WS_XE  0                       // [NBN][DMD]
#define WS_PW  (WS_XE + NBN*DMD)       // [BB][2]
#define WS_VEC (WS_PW + 4)             // 9*128
#define WS_OB  (WS_VEC + 9*DMD)        // [NBN][DMD][DMD] branch-0 output
// branch-1 output lives in d_out (read then overwritten by k_out)

// ---------------- xe: 4 n's per block, float4-staged x ----------------
__global__ __launch_bounds__(512) void k_xe(const float* __restrict__ x,
                                            const float* __restrict__ W_emb,
                                            const float* __restrict__ b_emb,
                                            float* __restrict__ ws) {
    int blk = blockIdx.x;              // 32 = 2 b x 16 n-groups
    int b = blk >> 4, n0 = (blk & 15) * 4;
    int tid = threadIdx.x;
    int t = tid & 127, sc = tid >> 7;
    __shared__ __align__(16) float4 xsh[SQ];
    __shared__ float part[3][DMD][4];
    xsh[tid] = *reinterpret_cast<const float4*>(&x[(b * SQ + tid) * NV + n0]);
    __syncthreads();
    float a0 = 0.f, a1 = 0.f, a2 = 0.f, a3 = 0.f;
    const float* W = W_emb + (sc * 128) * DMD + t;
#pragma unroll 8
    for (int s = 0; s < 128; ++s) {
        float w = W[s * DMD];
        float4 xv = xsh[sc * 128 + s];
        a0 = fmaf(xv.x, w, a0); a1 = fmaf(xv.y, w, a1);
        a2 = fmaf(xv.z, w, a2); a3 = fmaf(xv.w, w, a3);
    }
    if (sc) {
        part[sc - 1][t][0] = a0; part[sc - 1][t][1] = a1;
        part[sc - 1][t][2] = a2; part[sc - 1][t][3] = a3;
    }
    __syncthreads();
    if (sc == 0) {
        float be = b_emb[t];
        float r0 = a0 + part[0][t][0] + part[1][t][0] + part[2][t][0] + be;
        float r1 = a1 + part[0][t][1] + part[1][t][1] + part[2][t][1] + be;
        float r2 = a2 + part[0][t][2] + part[1][t][2] + part[2][t][2] + be;
        float r3 = a3 + part[0][t][3] + part[1][t][3] + part[2][t][3] + be;
        ws[WS_XE + (b * NV + n0 + 0) * DMD + t] = r0;
        ws[WS_XE + (b * NV + n0 + 1) * DMD + t] = r1;
        ws[WS_XE + (b * NV + n0 + 2) * DMD + t] = r2;
        ws[WS_XE + (b * NV + n0 + 3) * DMD + t] = r3;
    }
}

// ---------------- merged: period weights (blocks 0,1) + rank-1 vectors (block 2) ----------------
__global__ __launch_bounds__(128) void k_prep(const int* __restrict__ f1p,
                                              const int* __restrict__ f2p,
                                              const float* __restrict__ Wel, const float* __restrict__ bel,
                                              const float* __restrict__ W_start, const float* __restrict__ b_start,
                                              const float* __restrict__ Wq, const float* __restrict__ bq,
                                              const float* __restrict__ Wk, const float* __restrict__ bk,
                                              const float* __restrict__ Wv, const float* __restrict__ bv,
                                              float* __restrict__ ws) {
    int tid = threadIdx.x;
    __shared__ float ct[DMD], st[DMD];
    __shared__ float a2[2];
    __shared__ __align__(16) float A[DMD], C[DMD], BL[DMD];
    if (blockIdx.x < 2) {
        int b = blockIdx.x;
        float ang = (float)tid * 0.04908738521234052f;   // 2*pi/128
        ct[tid] = cosf(ang);
        st[tid] = sinf(ang);
        __syncthreads();
        int k = tid >> 6;
        int n = tid & 63;
        int f = k ? f2p[0] : f1p[0];
        const float* xr = ws + WS_XE + (b * NV + n) * DMD;
        float re = 0.f, im = 0.f;
#pragma unroll 8
        for (int t = 0; t < DMD; ++t) {
            int ph = (f * t) & (DMD - 1);
            float v = xr[t];
            re = fmaf(v, ct[ph], re);
            im = fmaf(v, st[ph], im);
        }
        float amp = sqrtf(re * re + im * im);
        for (int off = 32; off > 0; off >>= 1) amp += __shfl_down(amp, off);
        if (n == 0) a2[k] = amp * (1.0f / NV);
        __syncthreads();
        if (tid == 0) {
            float m = fmaxf(a2[0], a2[1]);
            float e0 = expf(a2[0] - m), e1 = expf(a2[1] - m);
            float inv = 1.0f / (e0 + e1);
            ws[WS_PW + b * 2 + 0] = e0 * inv;
            ws[WS_PW + b * 2 + 1] = e1 * inv;
        }
    } else {
        int e = tid;
        float a = 0.f, c = 0.f;
        const float4* We4 = reinterpret_cast<const float4*>(Wel + e * DMD);
        const float4* Ws4 = reinterpret_cast<const float4*>(W_start);
        const float4* Bs4 = reinterpret_cast<const float4*>(b_start);
#pragma unroll 8
        for (int d4 = 0; d4 < 32; ++d4) {
            float4 w = We4[d4], s4 = Ws4[d4], t4 = Bs4[d4];
            a = fmaf(w.x, s4.x, fmaf(w.y, s4.y, fmaf(w.z, s4.z, fmaf(w.w, s4.w, a))));
            c = fmaf(w.x, t4.x, fmaf(w.y, t4.y, fmaf(w.z, t4.z, fmaf(w.w, t4.w, c))));
        }
        A[e] = a;
        C[e] = c + bel[e];
        BL[e] = bel[e];
        __syncthreads();
        float aq = 0, cq = 0, pq = 0, ak = 0, ck = 0, pk = 0, av = 0, cv = 0, pv = 0;
        const float4* Wq4 = reinterpret_cast<const float4*>(Wq + e * DMD);
        const float4* Wk4 = reinterpret_cast<const float4*>(Wk + e * DMD);
        const float4* Wv4 = reinterpret_cast<const float4*>(Wv + e * DMD);
        const float4* A4 = reinterpret_cast<const float4*>(A);
        const float4* C4 = reinterpret_cast<const float4*>(C);
        const float4* B4 = reinterpret_cast<const float4*>(BL);
#pragma unroll 4
        for (int d4 = 0; d4 < 32; ++d4) {
            float4 Ad = A4[d4], Cd = C4[d4], Bd = B4[d4];
            float4 wq = Wq4[d4], wk = Wk4[d4], wv = Wv4[d4];
            aq = fmaf(wq.x, Ad.x, fmaf(wq.y, Ad.y, fmaf(wq.z, Ad.z, fmaf(wq.w, Ad.w, aq))));
            cq = fmaf(wq.x, Cd.x, fmaf(wq.y, Cd.y, fmaf(wq.z, Cd.z, fmaf(wq.w, Cd.w, cq))));
            pq = fmaf(wq.x, Bd.x, fmaf(wq.y, Bd.y, fmaf(wq.z, Bd.z, fmaf(wq.w, Bd.w, pq))));
            ak = fmaf(wk.x, Ad.x, fmaf(wk.y, Ad.y, fmaf(wk.z, Ad.z, fmaf(wk.w, Ad.w, ak))));
            ck = fmaf(wk.x, Cd.x, fmaf(wk.y, Cd.y, fmaf(wk.z, Cd.z, fmaf(wk.w, Cd.w, ck))));
            pk = fmaf(wk.x, Bd.x, fmaf(wk.y, Bd.y, fmaf(wk.z, Bd.z, fmaf(wk.w, Bd.w, pk))));
            av = fmaf(wv.x, Ad.x, fmaf(wv.y, Ad.y, fmaf(wv.z, Ad.z, fmaf(wv.w, Ad.w, av))));
            cv = fmaf(wv.x, Cd.x, fmaf(wv.y, Cd.y, fmaf(wv.z, Cd.z, fmaf(wv.w, Cd.w, cv))));
            pv = fmaf(wv.x, Bd.x, fmaf(wv.y, Bd.y, fmaf(wv.z, Bd.z, fmaf(wv.w, Bd.w, pv))));
        }
        float* V = ws + WS_VEC;
        V[0 * DMD + e] = aq; V[1 * DMD + e] = cq + bq[e]; V[2 * DMD + e] = pq + bq[e];
        V[3 * DMD + e] = ak; V[4 * DMD + e] = ck + bk[e]; V[5 * DMD + e] = pk + bk[e];
        V[6 * DMD + e] = av; V[7 * DMD + e] = cv + bv[e]; V[8 * DMD + e] = pv + bv[e];
    }
}

// ============ attention paths (8 e's per block, single branch, direct stores) ============

// Rank-1: P == 128 (f == 1)
__device__ __forceinline__ void attn_rank1(float pwv, const float (*Vsh)[8],
                                           const float* xs, float* __restrict__ ob,
                                           int rowbase, int tid) {
    float xi = xs[tid];
    float t[8], l[8], ax[8];
#pragma unroll
    for (int k = 0; k < 8; ++k) {
        t[k] = CSC * fmaf(xi, Vsh[0][k], Vsh[1][k]) * Vsh[3][k];
        l[k] = 0.f; ax[k] = 0.f;
    }
#pragma unroll 4
    for (int j = 0; j < DMD; ++j) {
        float xj = xs[j];
#pragma unroll
        for (int k = 0; k < 8; ++k) {
            float ev = exp2f(t[k] * xj);
            l[k] += ev;
            ax[k] = fmaf(ev, xj, ax[k]);
        }
    }
#pragma unroll
    for (int k = 0; k < 8; ++k) {
        float o = fmaf(Vsh[6][k], ax[k] / l[k], Vsh[7][k]);
        ob[rowbase + k * DMD + tid] = pwv * o;
    }
}

// pow2-P path: P in {32,64}; EB e's batched per pass
template<int PP, int NP, int EB>
__device__ __forceinline__ void attn_pow2(float pwv, const float (*Vsh)[8],
                                          const float* xs, float* __restrict__ ob,
                                          int rowbase, int tid) {
    const int UH = PP / 4;
    int lane4 = tid & 3, i0 = tid >> 2, jb = lane4 * UH;

    float xq[NP][UH], U2[UH];
#pragma unroll
    for (int u = 0; u < UH; ++u) {
        int j = jb + u;
        float s = 0.f;
#pragma unroll
        for (int q = 0; q < NP; ++q) { float xv = xs[q * PP + j]; xq[q][u] = xv; s += xv; }
        U2[u] = s;
    }
    const int NREP = (PP == 64) ? 2 : 1;
#pragma unroll
    for (int rep = 0; rep < NREP; ++rep) {
        int i = i0 + rep * 32;
        float G2[UH];
#pragma unroll
        for (int u = 0; u < UH; ++u) G2[u] = 0.f;
#pragma unroll
        for (int q = 0; q < NP; ++q) {
            float xi = xs[q * PP + i];
#pragma unroll
            for (int u = 0; u < UH; ++u) G2[u] = fmaf(xi, xq[q][u], G2[u]);
        }
#pragma unroll
        for (int eg = 0; eg < 8; eg += EB) {
            float d1[EB], d2[EB], l[EB];
            float accq[NP][EB];
#pragma unroll
            for (int k = 0; k < EB; ++k) {
                float t = CSC * Vsh[3][eg + k];
                d1[k] = t * Vsh[0][eg + k];
                d2[k] = t * Vsh[1][eg + k];
                l[k] = 0.f;
#pragma unroll
                for (int q = 0; q < NP; ++q) accq[q][k] = 0.f;
            }
#pragma unroll
            for (int u = 0; u < UH; ++u) {
                float gg = G2[u], uu = U2[u];
                float ev[EB];
#pragma unroll
                for (int k = 0; k < EB; ++k) ev[k] = exp2f(fmaf(d1[k], gg, d2[k] * uu));
#pragma unroll
                for (int k = 0; k < EB; ++k) {
                    l[k] += ev[k];
#pragma unroll
                    for (int q = 0; q < NP; ++q) accq[q][k] = fmaf(ev[k], xq[q][u], accq[q][k]);
                }
            }
#pragma unroll
            for (int k = 0; k < EB; ++k) { l[k] += __shfl_xor(l[k], 1); l[k] += __shfl_xor(l[k], 2); }
#pragma unroll
            for (int q = 0; q < NP; ++q)
#pragma unroll
                for (int k = 0; k < EB; ++k) {
                    accq[q][k] += __shfl_xor(accq[q][k], 1);
                    accq[q][k] += __shfl_xor(accq[q][k], 2);
                }
            if (lane4 == 0) {
#pragma unroll
                for (int k = 0; k < EB; ++k) {
                    float li = 1.f / l[k];
                    float Av = Vsh[6][eg + k], Cv = Vsh[7][eg + k];
#pragma unroll
                    for (int q = 0; q < NP; ++q) {
                        float o = fmaf(Av, accq[q][k] * li, Cv);
                        ob[rowbase + (eg + k) * DMD + i * NP + q] = pwv * o;
                    }
                }
            }
        }
    }
}

// small-P path: P <= 16. Scores for all 8 e's computed once (2 slots/thread) -> LDS W,
// single barrier, PV thread-per-output.
template<int UB>
__device__ __forceinline__ void attn_small(
    int P, int pn, int r, int Prows, float pwv,
    const float (*Vsh)[8], const float* xs, const float* U, const float* xt,
    float* W, float* __restrict__ ob, int rowbase, int tid)
{
    int GP = P + 1;
    int tot = Prows * P;
    unsigned mP = (4096u + (unsigned)P - 1u) / (unsigned)P;     // ceil(4096/P)
    unsigned mpn = (4096u + (unsigned)pn - 1u) / (unsigned)pn;  // ceil(4096/pn)

    // ---- slot 0 (score idx = tid) ----
    bool v0 = (tid < tot);
    int i0 = (int)(((unsigned)tid * mP) >> 12);
    int j0 = tid - i0 * P;
    bool A0 = (i0 < r), c0 = (j0 < r);
    float xtj0 = xt[j0], Uj0 = U[j0];
    float xti0 = A0 ? xt[i0] : 0.f;
    float g0 = 0.f;
    for (int p = 0; p < pn - 1; ++p) g0 = fmaf(xs[p * P + i0], xs[p * P + j0], g0);
    float Gx0 = (A0 && c0) ? fmaf(xti0, xtj0, g0) : g0;
    float Ux0 = (A0 && c0) ? Uj0 + xtj0 : Uj0;
    float Xw0 = (!A0 && c0) ? xtj0 : 0.f;
    float mw0 = c0 ? 1.f : 0.f;
    int wa0 = i0 * GP + j0;

    // ---- slot 1 (score idx = tid + 128) ----
    int idx1 = tid + 128;
    bool v1 = (idx1 < tot);
    int idx1c = v1 ? idx1 : 0;
    int i1 = (int)(((unsigned)idx1c * mP) >> 12);
    int j1 = idx1c - i1 * P;
    bool A1 = (i1 < r), c1 = (j1 < r);
    float xtj1 = xt[j1], Uj1 = U[j1];
    float xti1 = A1 ? xt[i1] : 0.f;
    float g1 = 0.f;
    for (int p = 0; p < pn - 1; ++p) g1 = fmaf(xs[p * P + i1], xs[p * P + j1], g1);
    float Gx1 = (A1 && c1) ? fmaf(xti1, xtj1, g1) : g1;
    float Ux1 = (A1 && c1) ? Uj1 + xtj1 : Uj1;
    float Xw1 = (!A1 && c1) ? xtj1 : 0.f;
    float mw1 = c1 ? 1.f : 0.f;
    int wa1 = i1 * GP + j1;

    // ---- PV assignment: output mo = tid -> (i2, p2) ----
    int i2 = (int)(((unsigned)tid * mpn) >> 12);
    int p2 = tid - i2 * pn;
    bool lastp = (p2 == pn - 1);
    int row2 = i2 * GP;
    float xsr[UB];
#pragma unroll
    for (int j = 0; j < UB; ++j) {
        int idx = p2 * P + j;
        xsr[j] = (j < P && idx < DMD) ? xs[idx] : 0.f;
    }

    // ---- score phase: 16 exps batched, one barrier ----
    float sv[8][2];
#pragma unroll
    for (int ec = 0; ec < 8; ++ec) {
        float Aq = Vsh[0][ec], Cq = Vsh[1][ec], Pq = Vsh[2][ec];
        float Ak = Vsh[3][ec], Ck = Vsh[4][ec], Pk = Vsh[5][ec];
        float t = CSC * Ak;
        float d1 = t * Aq, d2 = t * Cq, d3 = t * Pq;
        float ckpk = CSC * (Ck - Pk);
        float aS0 = A0 ? fmaf(Aq, xti0, Cq) : Pq;
        sv[ec][0] = fmaf(d1, Gx0, fmaf(d2, Ux0, fmaf(d3, Xw0, (ckpk * aS0) * mw0)));
        float aS1 = A1 ? fmaf(Aq, xti1, Cq) : Pq;
        sv[ec][1] = fmaf(d1, Gx1, fmaf(d2, Ux1, fmaf(d3, Xw1, (ckpk * aS1) * mw1)));
    }
#pragma unroll
    for (int ec = 0; ec < 8; ++ec) { sv[ec][0] = exp2f(sv[ec][0]); sv[ec][1] = exp2f(sv[ec][1]); }
#pragma unroll
    for (int ec = 0; ec < 8; ++ec) {
        if (v0) W[ec * 288 + wa0] = sv[ec][0];
        if (v1) W[ec * 288 + wa1] = sv[ec][1];
    }
    __syncthreads();

    // ---- PV phase ----
#pragma unroll
    for (int ec = 0; ec < 8; ++ec) {
        float Av = Vsh[6][ec], Cv = Vsh[7][ec], Pv = Vsh[8][ec];
        float l = 0.f, wr = 0.f, ax = 0.f;
#pragma unroll
        for (int j = 0; j < UB; ++j) {
            float w = W[ec * 288 + row2 + ((j < P) ? j : 0)];
            w = (j < P) ? w : 0.f;
            l += w;
            wr += (j < r) ? w : 0.f;
            ax = fmaf(w, xsr[j], ax);
        }
        float li = 1.f / l;
        float o;
        if (lastp) { float sl = wr * li; o = fmaf(Av, ax * li, fmaf(Cv, sl, Pv * (1.f - sl))); }
        else       o = fmaf(Av, ax * li, Cv);
        ob[rowbase + ec * DMD + tid] = pwv * o;
    }
}

// mid-P path (P in {18,21,25,42}): register scheme with masks
template<int UH, int NP>
__device__ __forceinline__ void attn_midA(
    int P, int pn, int r, int Prows, float pwv,
    const float (*Vsh)[8], const float* xs, const float* U,
    const float* xt, float* __restrict__ ob, int rowbase, int tid)
{
    int lane4 = tid & 3;
    int i0 = tid >> 2;
    int jb = lane4 * UH;

    float Ur[UH], xtr[UH], xq0[UH], xq1[UH];
#pragma unroll
    for (int u = 0; u < UH; ++u) {
        int j = jb + u, jc = (j < P) ? j : 0;
        Ur[u] = U[jc];
        xtr[u] = xt[jc];
        xq0[u] = (j < DMD) ? xs[j] : 0.f;
        int i1x = P + j;
        xq1[u] = (i1x < DMD) ? xs[i1x] : 0.f;
    }
    int nrep = (Prows > 32) ? 2 : 1;
    for (int rep = 0; rep < nrep; ++rep) {
        int i = i0 + rep * 32;
        bool rowact = (i < Prows);
        int ic = rowact ? i : 0;
        float xtic = xt[ic];
        bool rowvalid = (ic < r);
        float g[UH];
#pragma unroll
        for (int u = 0; u < UH; ++u) g[u] = 0.f;
        for (int p = 0; p < pn - 1; ++p) {
            float xi = xs[p * P + ic];
#pragma unroll
            for (int u = 0; u < UH; ++u) {
                int j = jb + u, jc = (j < P) ? j : 0;
                g[u] = fmaf(xi, xs[p * P + jc], g[u]);
            }
        }
        for (int ec = 0; ec < 8; ++ec) {
            float Aq = Vsh[0][ec], Cq = Vsh[1][ec], Pq = Vsh[2][ec];
            float Ak = Vsh[3][ec], Ck = Vsh[4][ec], Pk = Vsh[5][ec];
            float Av = Vsh[6][ec], Cv = Vsh[7][ec], Pv = Vsh[8][ec];
            float c1 = CSC * Aq * Ak, c3 = CSC * Cq * Ak;
            float asi = CSC * (rowvalid ? fmaf(xtic, Aq, Cq) : Pq);

            float l0 = 0.f, l1 = 0.f, w0 = 0.f, w1 = 0.f;
            float accq[NP];
#pragma unroll
            for (int q = 0; q < NP; ++q) accq[q] = 0.f;
#pragma unroll
            for (int u = 0; u < UH; ++u) {
                int j = jb + u;
                float bK = (j < r) ? fmaf(xtr[u], Ak, Ck) : Pk;
                float S = fmaf(asi, bK, fmaf(c3, Ur[u], c1 * g[u]));
                float ev = exp2f(S);
                ev = (j < P) ? ev : 0.f;
                if (u & 1) l1 += ev; else l0 += ev;
                float evr = (j < r) ? ev : 0.f;
                if (u & 1) w1 += evr; else w0 += evr;
                accq[0] = fmaf(ev, xq0[u], accq[0]);
                if (NP >= 2) accq[1] = fmaf(ev, xq1[u], accq[1]);
#pragma unroll
                for (int q = 2; q < NP; ++q) {
                    int idx = q * P + j;
                    float xv = (idx < DMD) ? xs[idx] : 0.f;
                    accq[q] = fmaf(ev, xv, accq[q]);
                }
            }
            float l = l0 + l1, wr = w0 + w1;
            l += __shfl_xor(l, 1);  l += __shfl_xor(l, 2);
            wr += __shfl_xor(wr, 1); wr += __shfl_xor(wr, 2);
#pragma unroll
            for (int q = 0; q < NP; ++q) {
                if (q < pn) {
                    accq[q] += __shfl_xor(accq[q], 1);
                    accq[q] += __shfl_xor(accq[q], 2);
                }
            }
            if (lane4 == 0 && rowact) {
                float li = 1.f / l;
#pragma unroll
                for (int q = 0; q < NP; ++q) {
                    if (q < pn) {
                        int mo = i * pn + q;
                        if (mo < DMD) {
                            float o;
                            if (q == pn - 1) {
                                float sl = wr * li;
                                o = fmaf(Av, accq[q] * li, fmaf(Cv, sl, Pv * (1.f - sl)));
                            } else {
                                o = fmaf(Av, accq[q] * li, Cv);
                            }
                            ob[rowbase + ec * DMD + mo] = pwv * o;
                        }
                    }
                }
            }
        }
    }
}

__global__ __launch_bounds__(128) void k_attn(const int* __restrict__ f1p,
                                              const int* __restrict__ f2p,
                                              float* __restrict__ ws,
                                              float* __restrict__ outb) {
    int bn = blockIdx.y, b = bn >> 6;
    int e0 = blockIdx.x * 8;           // 16 chunks of 8 e's
    int br = blockIdx.z;
    int tid = threadIdx.x;

    __shared__ float xs[DMD], U[64], xt[64];
    __shared__ float Vsh[9][8];
    __shared__ float W[8 * 288];

    xs[tid] = ws[WS_XE + bn * DMD + tid];
    if (tid < 72) Vsh[tid >> 3][tid & 7] = ws[WS_VEC + (tid >> 3) * DMD + e0 + (tid & 7)];
    int f = br ? f2p[0] : f1p[0];
    float pwv = ws[WS_PW + b * 2 + br];
    float* ob = br ? outb : (ws + WS_OB);
    int rowbase = (bn * DMD + e0) * DMD;
    __syncthreads();

    int P = DMD / f;
    int pn = (DMD + P - 1) / P;
    int r = DMD - (pn - 1) * P;
    int Prows = (DMD + pn - 1) / pn;

    if (P == DMD) {
        attn_rank1(pwv, Vsh, xs, ob, rowbase, tid);
        return;
    }
    if (tid < P) {
        float s = 0.f;
        for (int p = 0; p < pn - 1; ++p) s += xs[p * P + tid];
        U[tid] = s;
        xt[tid] = (tid < r) ? xs[(pn - 1) * P + tid] : 0.f;
    }
    __syncthreads();

    if (P <= 4)       attn_small<4>(P, pn, r, Prows, pwv, Vsh, xs, U, xt, W, ob, rowbase, tid);
    else if (P <= 8)  attn_small<8>(P, pn, r, Prows, pwv, Vsh, xs, U, xt, W, ob, rowbase, tid);
    else if (P <= 16) attn_small<16>(P, pn, r, Prows, pwv, Vsh, xs, U, xt, W, ob, rowbase, tid);
    else if (P == 64) attn_pow2<64, 2, 4>(pwv, Vsh, xs, ob, rowbase, tid);
    else if (P == 32) attn_pow2<32, 4, 4>(pwv, Vsh, xs, ob, rowbase, tid);
    else if (P > 32)  attn_midA<16, 4>(P, pn, r, Prows, pwv, Vsh, xs, U, xt, ob, rowbase, tid);  // P=42
    else              attn_midA<8, 8>(P, pn, r, Prows, pwv, Vsh, xs, U, xt, ob, rowbase, tid);   // 18,21,25
}

// ---------------- out[bn][e][h] = sum_m (ob0+ob1)[bn][e][m]*Wo[h][m] + bo[h] ----------------
__global__ __launch_bounds__(256) void k_out(const float* __restrict__ Wo,
                                             const float* __restrict__ bo,
                                             const float* __restrict__ ws,
                                             float* __restrict__ out) {
    int blk = blockIdx.x;          // 256 = 64 bn-pairs * 4 e-quarters
    int bn0 = (blk >> 2) * 2;
    int e0  = (blk & 3) * 32;
    int tid = threadIdx.x;
    __shared__ __align__(16) float WTc[32 * 132];    // [mm][h]
    __shared__ __align__(16) float oT[2][32][36];    // [bnl][mm][e]
    int hg = tid & 31, eg = tid >> 5, h0 = hg * 4;

    float acc[2][4][4];
#pragma unroll
    for (int a = 0; a < 2; ++a)
#pragma unroll
        for (int c = 0; c < 4; ++c)
#pragma unroll
            for (int d = 0; d < 4; ++d) acc[a][c][d] = 0.f;

    for (int mc = 0; mc < 4; ++mc) {
        int m0 = mc * 32;
        __syncthreads();
        for (int idx = tid; idx < 4096; idx += 256) {
            int h = idx >> 5, mm = idx & 31;
            WTc[mm * 132 + h] = Wo[h * DMD + m0 + mm];
        }
        for (int idx = tid; idx < 2048; idx += 256) {
            int bnl = idx >> 10, rem = idx & 1023, e = rem >> 5, mm = rem & 31;
            int gi = ((bn0 + bnl) * DMD + e0 + e) * DMD + m0 + mm;
            oT[bnl][mm][e] = ws[WS_OB + gi] + out[gi];
        }
        __syncthreads();
#pragma unroll 4
        for (int mm = 0; mm < 32; ++mm) {
            const float4 wv = *reinterpret_cast<const float4*>(&WTc[mm * 132 + h0]);
            const float4 q0 = *reinterpret_cast<const float4*>(&oT[0][mm][eg * 4]);
            const float4 q1 = *reinterpret_cast<const float4*>(&oT[1][mm][eg * 4]);
            float ae[2][4] = {{q0.x, q0.y, q0.z, q0.w}, {q1.x, q1.y, q1.z, q1.w}};
#pragma unroll
            for (int bnl = 0; bnl < 2; ++bnl) {
#pragma unroll
                for (int el = 0; el < 4; ++el) {
                    float a = ae[bnl][el];
                    acc[bnl][el][0] = fmaf(a, wv.x, acc[bnl][el][0]);
                    acc[bnl][el][1] = fmaf(a, wv.y, acc[bnl][el][1]);
                    acc[bnl][el][2] = fmaf(a, wv.z, acc[bnl][el][2]);
                    acc[bnl][el][3] = fmaf(a, wv.w, acc[bnl][el][3]);
                }
            }
        }
    }
    const float4 bov = *reinterpret_cast<const float4*>(&bo[h0]);
#pragma unroll
    for (int bnl = 0; bnl < 2; ++bnl) {
#pragma unroll
        for (int el = 0; el < 4; ++el) {
            float4 res = { acc[bnl][el][0] + bov.x, acc[bnl][el][1] + bov.y,
                           acc[bnl][el][2] + bov.z, acc[bnl][el][3] + bov.w };
            int e = e0 + eg * 4 + el;
            *reinterpret_cast<float4*>(&out[((bn0 + bnl) * DMD + e) * DMD + h0]) = res;
        }
    }
}

extern "C" void kernel_launch(void* const* d_in, const int* in_sizes, int n_in,
                              void* d_out, int out_size, void* d_ws, size_t ws_size,
                              hipStream_t stream) {
    const float* x       = (const float*)d_in[0];
    const float* W_emb   = (const float*)d_in[1];
    const float* b_emb   = (const float*)d_in[2];
    const float* W_start = (const float*)d_in[3];
    const float* b_start = (const float*)d_in[4];
    const float* Wel     = (const float*)d_in[5];
    const float* bel     = (const float*)d_in[6];
    const float* Wq      = (const float*)d_in[7];
    const float* bq      = (const float*)d_in[8];
    const float* Wk      = (const float*)d_in[9];
    const float* bk      = (const float*)d_in[10];
    const float* Wv      = (const float*)d_in[11];
    const float* bv      = (const float*)d_in[12];
    const float* Wo      = (const float*)d_in[13];
    const float* bo      = (const float*)d_in[14];
    const int*   f1p     = (const int*)d_in[15];
    const int*   f2p     = (const int*)d_in[16];
    float* ws  = (float*)d_ws;
    float* out = (float*)d_out;

    k_xe<<<32, 512, 0, stream>>>(x, W_emb, b_emb, ws);
    k_prep<<<3, 128, 0, stream>>>(f1p, f2p, Wel, bel, W_start, b_start,
                                  Wq, bq, Wk, bk, Wv, bv, ws);
    k_attn<<<dim3(16, NBN, 2), 128, 0, stream>>>(f1p, f2p, ws, out);
    k_out<<<256, 256, 0, stream>>>(Wo, bo, ws, out);
}

// Round 8
// 85.215 us; speedup vs baseline: 1.1037x; 1.1037x over previous
//
#include <hip/hip_runtime.h>

#define DMD 128
#define NV 64
#define BB 2
#define SQ 512
#define NBN 128                 // BB*NV
#define ASCALE 0.08838834764831845f   // 128^-0.5
#define L2E 1.4426950408889634f
#define CSC (ASCALE * L2E)

// workspace layout (float offsets)
#define WS_XE  0                       // [NBN][DMD]
#define WS_VEC (WS_XE + NBN*DMD)       // 9*128
#define WS_OB  (WS_VEC + 9*DMD)        // [NBN][DMD][DMD] branch-0 output
#define WS_AMP (WS_OB + NBN*DMD*DMD)   // [BB][NV][2] DFT magnitudes
// branch-1 output lives in d_out (read then overwritten by k_out)

// ---------------- xe + per-(b,n) DFT mags (blocks 0-31) + rank-1 vectors (block 32) ------------
__global__ __launch_bounds__(512) void k_xe(const float* __restrict__ x,
                                            const float* __restrict__ W_emb,
                                            const float* __restrict__ b_emb,
                                            const int* __restrict__ f1p,
                                            const int* __restrict__ f2p,
                                            const float* __restrict__ Wel, const float* __restrict__ bel,
                                            const float* __restrict__ W_start, const float* __restrict__ b_start,
                                            const float* __restrict__ Wq, const float* __restrict__ bq,
                                            const float* __restrict__ Wk, const float* __restrict__ bk,
                                            const float* __restrict__ Wv, const float* __restrict__ bv,
                                            float* __restrict__ ws) {
    int blk = blockIdx.x;
    int tid = threadIdx.x;
    __shared__ __align__(16) float4 xsh[SQ];
    __shared__ float part[3][DMD][4];
    __shared__ float red[2][16];
    __shared__ __align__(16) float A[DMD], C[DMD], BL[DMD];

    if (blk < 32) {
        int b = blk >> 4, n0 = (blk & 15) * 4;
        int t = tid & 127, sc = tid >> 7;
        xsh[tid] = *reinterpret_cast<const float4*>(&x[(b * SQ + tid) * NV + n0]);
        __syncthreads();
        float a0 = 0.f, a1 = 0.f, a2 = 0.f, a3 = 0.f;
        const float* W = W_emb + (sc * 128) * DMD + t;
#pragma unroll 8
        for (int s = 0; s < 128; ++s) {
            float w = W[s * DMD];
            float4 xv = xsh[sc * 128 + s];
            a0 = fmaf(xv.x, w, a0); a1 = fmaf(xv.y, w, a1);
            a2 = fmaf(xv.z, w, a2); a3 = fmaf(xv.w, w, a3);
        }
        if (sc) {
            part[sc - 1][t][0] = a0; part[sc - 1][t][1] = a1;
            part[sc - 1][t][2] = a2; part[sc - 1][t][3] = a3;
        }
        __syncthreads();
        if (sc == 0) {
            float be = b_emb[t];
            float r0 = a0 + part[0][t][0] + part[1][t][0] + part[2][t][0] + be;
            float r1 = a1 + part[0][t][1] + part[1][t][1] + part[2][t][1] + be;
            float r2 = a2 + part[0][t][2] + part[1][t][2] + part[2][t][2] + be;
            float r3 = a3 + part[0][t][3] + part[1][t][3] + part[2][t][3] + be;
            ws[WS_XE + (b * NV + n0 + 0) * DMD + t] = r0;
            ws[WS_XE + (b * NV + n0 + 1) * DMD + t] = r1;
            ws[WS_XE + (b * NV + n0 + 2) * DMD + t] = r2;
            ws[WS_XE + (b * NV + n0 + 3) * DMD + t] = r3;
            // DFT at f1,f2 over t (linear reduce across the 2 sc==0 waves)
            int f1v = f1p[0], f2v = f2p[0];
            float angA = (float)((f1v * t) & 127) * 0.04908738521234052f;
            float angB = (float)((f2v * t) & 127) * 0.04908738521234052f;
            float cA = cosf(angA), sA = sinf(angA);
            float cB = cosf(angB), sB = sinf(angB);
            float vals[16] = { r0*cA, r0*sA, r0*cB, r0*sB,
                               r1*cA, r1*sA, r1*cB, r1*sB,
                               r2*cA, r2*sA, r2*cB, r2*sB,
                               r3*cA, r3*sA, r3*cB, r3*sB };
#pragma unroll
            for (int k = 0; k < 16; ++k) {
                float v = vals[k];
                v += __shfl_xor(v, 1);  v += __shfl_xor(v, 2);
                v += __shfl_xor(v, 4);  v += __shfl_xor(v, 8);
                v += __shfl_xor(v, 16); v += __shfl_xor(v, 32);
                vals[k] = v;
            }
            if ((tid & 63) == 0) {
                int w = tid >> 6;
#pragma unroll
                for (int k = 0; k < 16; ++k) red[w][k] = vals[k];
            }
        }
        __syncthreads();
        if (tid < 8) {
            int nl = tid >> 1, fs = tid & 1;
            int base = nl * 4 + fs * 2;
            float re = red[0][base] + red[1][base];
            float im = red[0][base + 1] + red[1][base + 1];
            ws[WS_AMP + (b * NV + n0 + nl) * 2 + fs] = sqrtf(re * re + im * im);
        }
    } else {
        // ---- rank-1 projected vectors (weights only) ----
        int e = tid;
        if (tid < 128) {
            float a = 0.f, c = 0.f;
            const float4* We4 = reinterpret_cast<const float4*>(Wel + e * DMD);
            const float4* Ws4 = reinterpret_cast<const float4*>(W_start);
            const float4* Bs4 = reinterpret_cast<const float4*>(b_start);
#pragma unroll 8
            for (int d4 = 0; d4 < 32; ++d4) {
                float4 w = We4[d4], s4 = Ws4[d4], t4 = Bs4[d4];
                a = fmaf(w.x, s4.x, fmaf(w.y, s4.y, fmaf(w.z, s4.z, fmaf(w.w, s4.w, a))));
                c = fmaf(w.x, t4.x, fmaf(w.y, t4.y, fmaf(w.z, t4.z, fmaf(w.w, t4.w, c))));
            }
            A[e] = a;
            C[e] = c + bel[e];
            BL[e] = bel[e];
        }
        __syncthreads();
        if (tid < 128) {
            float aq = 0, cq = 0, pq = 0, ak = 0, ck = 0, pk = 0, av = 0, cv = 0, pv = 0;
            const float4* Wq4 = reinterpret_cast<const float4*>(Wq + e * DMD);
            const float4* Wk4 = reinterpret_cast<const float4*>(Wk + e * DMD);
            const float4* Wv4 = reinterpret_cast<const float4*>(Wv + e * DMD);
            const float4* A4 = reinterpret_cast<const float4*>(A);
            const float4* C4 = reinterpret_cast<const float4*>(C);
            const float4* B4 = reinterpret_cast<const float4*>(BL);
#pragma unroll 4
            for (int d4 = 0; d4 < 32; ++d4) {
                float4 Ad = A4[d4], Cd = C4[d4], Bd = B4[d4];
                float4 wq = Wq4[d4], wk = Wk4[d4], wv = Wv4[d4];
                aq = fmaf(wq.x, Ad.x, fmaf(wq.y, Ad.y, fmaf(wq.z, Ad.z, fmaf(wq.w, Ad.w, aq))));
                cq = fmaf(wq.x, Cd.x, fmaf(wq.y, Cd.y, fmaf(wq.z, Cd.z, fmaf(wq.w, Cd.w, cq))));
                pq = fmaf(wq.x, Bd.x, fmaf(wq.y, Bd.y, fmaf(wq.z, Bd.z, fmaf(wq.w, Bd.w, pq))));
                ak = fmaf(wk.x, Ad.x, fmaf(wk.y, Ad.y, fmaf(wk.z, Ad.z, fmaf(wk.w, Ad.w, ak))));
                ck = fmaf(wk.x, Cd.x, fmaf(wk.y, Cd.y, fmaf(wk.z, Cd.z, fmaf(wk.w, Cd.w, ck))));
                pk = fmaf(wk.x, Bd.x, fmaf(wk.y, Bd.y, fmaf(wk.z, Bd.z, fmaf(wk.w, Bd.w, pk))));
                av = fmaf(wv.x, Ad.x, fmaf(wv.y, Ad.y, fmaf(wv.z, Ad.z, fmaf(wv.w, Ad.w, av))));
                cv = fmaf(wv.x, Cd.x, fmaf(wv.y, Cd.y, fmaf(wv.z, Cd.z, fmaf(wv.w, Cd.w, cv))));
                pv = fmaf(wv.x, Bd.x, fmaf(wv.y, Bd.y, fmaf(wv.z, Bd.z, fmaf(wv.w, Bd.w, pv))));
            }
            float* V = ws + WS_VEC;
            V[0 * DMD + e] = aq; V[1 * DMD + e] = cq + bq[e]; V[2 * DMD + e] = pq + bq[e];
            V[3 * DMD + e] = ak; V[4 * DMD + e] = ck + bk[e]; V[5 * DMD + e] = pk + bk[e];
            V[6 * DMD + e] = av; V[7 * DMD + e] = cv + bv[e]; V[8 * DMD + e] = pv + bv[e];
        }
    }
}

// ============ attention paths (4 e's per block, single branch, direct stores) ============

// Rank-1: P == 128 (f == 1)
__device__ __forceinline__ void attn_rank1(float pwv, const float (*Vsh)[4],
                                           const float* xs, float* __restrict__ ob,
                                           int rowbase, int tid) {
    float xi = xs[tid];
    float t[4], l[4], ax[4];
#pragma unroll
    for (int k = 0; k < 4; ++k) {
        float Aq = Vsh[0][k], Cq = Vsh[1][k], Ak = Vsh[3][k];
        t[k] = CSC * fmaf(xi, Aq, Cq) * Ak;
        l[k] = 0.f; ax[k] = 0.f;
    }
#pragma unroll 4
    for (int j = 0; j < DMD; ++j) {
        float xj = xs[j];
#pragma unroll
        for (int k = 0; k < 4; ++k) {
            float ev = exp2f(t[k] * xj);
            l[k] += ev;
            ax[k] = fmaf(ev, xj, ax[k]);
        }
    }
#pragma unroll
    for (int k = 0; k < 4; ++k) {
        float Av = Vsh[6][k], Cv = Vsh[7][k];
        float o = fmaf(Av, ax[k] / l[k], Cv);
        ob[rowbase + k * DMD + tid] = pwv * o;
    }
}

// pow2-P path: P in {32,64}, no padding; EB e's batched per pass
template<int PP, int NP, int EB>
__device__ __forceinline__ void attn_pow2(float pwv, const float (*Vsh)[4],
                                          const float* xs, float* __restrict__ ob,
                                          int rowbase, int tid) {
    const int UH = PP / 4;
    int lane4 = tid & 3, i0 = tid >> 2, jb = lane4 * UH;

    float xq[NP][UH], U2[UH];
#pragma unroll
    for (int u = 0; u < UH; ++u) {
        int j = jb + u;
        float s = 0.f;
#pragma unroll
        for (int q = 0; q < NP; ++q) { float xv = xs[q * PP + j]; xq[q][u] = xv; s += xv; }
        U2[u] = s;
    }
    const int NREP = (PP == 64) ? 2 : 1;
#pragma unroll
    for (int rep = 0; rep < NREP; ++rep) {
        int i = i0 + rep * 32;
        float G2[UH];
#pragma unroll
        for (int u = 0; u < UH; ++u) G2[u] = 0.f;
#pragma unroll
        for (int q = 0; q < NP; ++q) {
            float xi = xs[q * PP + i];
#pragma unroll
            for (int u = 0; u < UH; ++u) G2[u] = fmaf(xi, xq[q][u], G2[u]);
        }
#pragma unroll
        for (int eg = 0; eg < 4; eg += EB) {
            float d1[EB], d2[EB], l[EB];
            float accq[NP][EB];
#pragma unroll
            for (int k = 0; k < EB; ++k) {
                float t = CSC * Vsh[3][eg + k];
                d1[k] = t * Vsh[0][eg + k];
                d2[k] = t * Vsh[1][eg + k];
                l[k] = 0.f;
#pragma unroll
                for (int q = 0; q < NP; ++q) accq[q][k] = 0.f;
            }
#pragma unroll
            for (int u = 0; u < UH; ++u) {
                float gg = G2[u], uu = U2[u];
                float ev[EB];
#pragma unroll
                for (int k = 0; k < EB; ++k) ev[k] = exp2f(fmaf(d1[k], gg, d2[k] * uu));
#pragma unroll
                for (int k = 0; k < EB; ++k) {
                    l[k] += ev[k];
#pragma unroll
                    for (int q = 0; q < NP; ++q) accq[q][k] = fmaf(ev[k], xq[q][u], accq[q][k]);
                }
            }
#pragma unroll
            for (int k = 0; k < EB; ++k) { l[k] += __shfl_xor(l[k], 1); l[k] += __shfl_xor(l[k], 2); }
#pragma unroll
            for (int q = 0; q < NP; ++q)
#pragma unroll
                for (int k = 0; k < EB; ++k) {
                    accq[q][k] += __shfl_xor(accq[q][k], 1);
                    accq[q][k] += __shfl_xor(accq[q][k], 2);
                }
            if (lane4 == 0) {
#pragma unroll
                for (int k = 0; k < EB; ++k) {
                    float li = 1.f / l[k];
                    float Av = Vsh[6][eg + k], Cv = Vsh[7][eg + k];
#pragma unroll
                    for (int q = 0; q < NP; ++q) {
                        float o = fmaf(Av, accq[q][k] * li, Cv);
                        ob[rowbase + (eg + k) * DMD + i * NP + q] = pwv * o;
                    }
                }
            }
        }
    }
}

// small-P path: P <= 16. Scores for all 4 e's computed once (2 slots/thread) -> LDS W,
// single barrier, PV thread-per-output.
template<int UB>
__device__ __forceinline__ void attn_small(
    int P, int pn, int r, int Prows, float pwv,
    const float (*Vsh)[4], const float* xs, const float* U, const float* xt,
    float* W, float* __restrict__ ob, int rowbase, int tid)
{
    int GP = P + 1;
    int tot = Prows * P;
    unsigned mP = (4096u + (unsigned)P - 1u) / (unsigned)P;     // ceil(4096/P)
    unsigned mpn = (4096u + (unsigned)pn - 1u) / (unsigned)pn;  // ceil(4096/pn)

    // ---- slot 0 (score idx = tid) ----
    bool v0 = (tid < tot);
    int i0 = (int)(((unsigned)tid * mP) >> 12);
    int j0 = tid - i0 * P;
    bool A0 = (i0 < r), c0 = (j0 < r);
    float xtj0 = xt[j0], Uj0 = U[j0];
    float xti0 = A0 ? xt[i0] : 0.f;
    float g0 = 0.f;
    for (int p = 0; p < pn - 1; ++p) g0 = fmaf(xs[p * P + i0], xs[p * P + j0], g0);
    float Gx0 = (A0 && c0) ? fmaf(xti0, xtj0, g0) : g0;
    float Ux0 = (A0 && c0) ? Uj0 + xtj0 : Uj0;
    float Xw0 = (!A0 && c0) ? xtj0 : 0.f;
    float mw0 = c0 ? 1.f : 0.f;
    int wa0 = i0 * GP + j0;

    // ---- slot 1 (score idx = tid + 128) ----
    int idx1 = tid + 128;
    bool v1 = (idx1 < tot);
    int idx1c = v1 ? idx1 : 0;
    int i1 = (int)(((unsigned)idx1c * mP) >> 12);
    int j1 = idx1c - i1 * P;
    bool A1 = (i1 < r), c1 = (j1 < r);
    float xtj1 = xt[j1], Uj1 = U[j1];
    float xti1 = A1 ? xt[i1] : 0.f;
    float g1 = 0.f;
    for (int p = 0; p < pn - 1; ++p) g1 = fmaf(xs[p * P + i1], xs[p * P + j1], g1);
    float Gx1 = (A1 && c1) ? fmaf(xti1, xtj1, g1) : g1;
    float Ux1 = (A1 && c1) ? Uj1 + xtj1 : Uj1;
    float Xw1 = (!A1 && c1) ? xtj1 : 0.f;
    float mw1 = c1 ? 1.f : 0.f;
    int wa1 = i1 * GP + j1;

    // ---- PV assignment: output mo = tid -> (i2, p2) ----
    int i2 = (int)(((unsigned)tid * mpn) >> 12);
    int p2 = tid - i2 * pn;
    bool lastp = (p2 == pn - 1);
    int row2 = i2 * GP;
    float xsr[UB];
#pragma unroll
    for (int j = 0; j < UB; ++j) {
        int idx = p2 * P + j;
        xsr[j] = (j < P && idx < DMD) ? xs[idx] : 0.f;
    }

    // ---- score phase: 8 exps batched, one barrier ----
    float s[4][2];
#pragma unroll
    for (int ec = 0; ec < 4; ++ec) {
        float Aq = Vsh[0][ec], Cq = Vsh[1][ec], Pq = Vsh[2][ec];
        float Ak = Vsh[3][ec], Ck = Vsh[4][ec], Pk = Vsh[5][ec];
        float t = CSC * Ak;
        float d1 = t * Aq, d2 = t * Cq, d3 = t * Pq;
        float ckpk = CSC * (Ck - Pk);
        float aS0 = A0 ? fmaf(Aq, xti0, Cq) : Pq;
        s[ec][0] = fmaf(d1, Gx0, fmaf(d2, Ux0, fmaf(d3, Xw0, (ckpk * aS0) * mw0)));
        float aS1 = A1 ? fmaf(Aq, xti1, Cq) : Pq;
        s[ec][1] = fmaf(d1, Gx1, fmaf(d2, Ux1, fmaf(d3, Xw1, (ckpk * aS1) * mw1)));
    }
#pragma unroll
    for (int ec = 0; ec < 4; ++ec) { s[ec][0] = exp2f(s[ec][0]); s[ec][1] = exp2f(s[ec][1]); }
#pragma unroll
    for (int ec = 0; ec < 4; ++ec) {
        if (v0) W[ec * 288 + wa0] = s[ec][0];
        if (v1) W[ec * 288 + wa1] = s[ec][1];
    }
    __syncthreads();

    // ---- PV phase ----
#pragma unroll
    for (int ec = 0; ec < 4; ++ec) {
        float Av = Vsh[6][ec], Cv = Vsh[7][ec], Pv = Vsh[8][ec];
        float l = 0.f, wr = 0.f, ax = 0.f;
#pragma unroll
        for (int j = 0; j < UB; ++j) {
            float w = W[ec * 288 + row2 + ((j < P) ? j : 0)];
            w = (j < P) ? w : 0.f;
            l += w;
            wr += (j < r) ? w : 0.f;
            ax = fmaf(w, xsr[j], ax);
        }
        float li = 1.f / l;
        float o;
        if (lastp) { float sl = wr * li; o = fmaf(Av, ax * li, fmaf(Cv, sl, Pv * (1.f - sl))); }
        else       o = fmaf(Av, ax * li, Cv);
        ob[rowbase + ec * DMD + tid] = pwv * o;
    }
}

// mid-P path (P in {18,21,25,42}): register scheme with masks
template<int UH, int NP>
__device__ __forceinline__ void attn_midA(
    int P, int pn, int r, int Prows, float pwv,
    const float (*Vsh)[4], const float* xs, const float* U,
    const float* xt, float* __restrict__ ob, int rowbase, int tid)
{
    int lane4 = tid & 3;
    int i0 = tid >> 2;
    int jb = lane4 * UH;

    float Ur[UH], xtr[UH], xq0[UH], xq1[UH];
#pragma unroll
    for (int u = 0; u < UH; ++u) {
        int j = jb + u, jc = (j < P) ? j : 0;
        Ur[u] = U[jc];
        xtr[u] = xt[jc];
        xq0[u] = (j < DMD) ? xs[j] : 0.f;
        int i1x = P + j;
        xq1[u] = (i1x < DMD) ? xs[i1x] : 0.f;
    }
    int nrep = (Prows > 32) ? 2 : 1;
    for (int rep = 0; rep < nrep; ++rep) {
        int i = i0 + rep * 32;
        bool rowact = (i < Prows);
        int ic = rowact ? i : 0;
        float xtic = xt[ic];
        bool rowvalid = (ic < r);
        float g[UH];
#pragma unroll
        for (int u = 0; u < UH; ++u) g[u] = 0.f;
        for (int p = 0; p < pn - 1; ++p) {
            float xi = xs[p * P + ic];
#pragma unroll
            for (int u = 0; u < UH; ++u) {
                int j = jb + u, jc = (j < P) ? j : 0;
                g[u] = fmaf(xi, xs[p * P + jc], g[u]);
            }
        }
        for (int ec = 0; ec < 4; ++ec) {
            float Aq = Vsh[0][ec], Cq = Vsh[1][ec], Pq = Vsh[2][ec];
            float Ak = Vsh[3][ec], Ck = Vsh[4][ec], Pk = Vsh[5][ec];
            float Av = Vsh[6][ec], Cv = Vsh[7][ec], Pv = Vsh[8][ec];
            float c1 = CSC * Aq * Ak, c3 = CSC * Cq * Ak;
            float asi = CSC * (rowvalid ? fmaf(xtic, Aq, Cq) : Pq);

            float l0 = 0.f, l1 = 0.f, w0 = 0.f, w1 = 0.f;
            float accq[NP];
#pragma unroll
            for (int q = 0; q < NP; ++q) accq[q] = 0.f;
#pragma unroll
            for (int u = 0; u < UH; ++u) {
                int j = jb + u;
                float bK = (j < r) ? fmaf(xtr[u], Ak, Ck) : Pk;
                float S = fmaf(asi, bK, fmaf(c3, Ur[u], c1 * g[u]));
                float ev = exp2f(S);
                ev = (j < P) ? ev : 0.f;
                if (u & 1) l1 += ev; else l0 += ev;
                float evr = (j < r) ? ev : 0.f;
                if (u & 1) w1 += evr; else w0 += evr;
                accq[0] = fmaf(ev, xq0[u], accq[0]);
                if (NP >= 2) accq[1] = fmaf(ev, xq1[u], accq[1]);
#pragma unroll
                for (int q = 2; q < NP; ++q) {
                    int idx = q * P + j;
                    float xv = (idx < DMD) ? xs[idx] : 0.f;
                    accq[q] = fmaf(ev, xv, accq[q]);
                }
            }
            float l = l0 + l1, wr = w0 + w1;
            l += __shfl_xor(l, 1);  l += __shfl_xor(l, 2);
            wr += __shfl_xor(wr, 1); wr += __shfl_xor(wr, 2);
#pragma unroll
            for (int q = 0; q < NP; ++q) {
                if (q < pn) {
                    accq[q] += __shfl_xor(accq[q], 1);
                    accq[q] += __shfl_xor(accq[q], 2);
                }
            }
            if (lane4 == 0 && rowact) {
                float li = 1.f / l;
#pragma unroll
                for (int q = 0; q < NP; ++q) {
                    if (q < pn) {
                        int mo = i * pn + q;
                        if (mo < DMD) {
                            float o;
                            if (q == pn - 1) {
                                float sl = wr * li;
                                o = fmaf(Av, accq[q] * li, fmaf(Cv, sl, Pv * (1.f - sl)));
                            } else {
                                o = fmaf(Av, accq[q] * li, Cv);
                            }
                            ob[rowbase + ec * DMD + mo] = pwv * o;
                        }
                    }
                }
            }
        }
    }
}

__global__ __launch_bounds__(128) void k_attn(const int* __restrict__ f1p,
                                              const int* __restrict__ f2p,
                                              float* __restrict__ ws,
                                              float* __restrict__ outb) {
    int bn = blockIdx.y, b = bn >> 6;
    int e0 = blockIdx.x * 4;           // 32 chunks of 4 e's
    int br = blockIdx.z;
    int tid = threadIdx.x;

    __shared__ float xs[DMD], U[64], xt[64];
    __shared__ float Vsh[9][4];
    __shared__ float W[4 * 288];
    __shared__ float pwsh[2];

    xs[tid] = ws[WS_XE + bn * DMD + tid];
    if (tid < 36) Vsh[tid >> 2][tid & 3] = ws[WS_VEC + (tid >> 2) * DMD + e0 + (tid & 3)];
    // wave 0: reduce DFT magnitudes -> period weights
    if (tid < 64) {
        float a0 = ws[WS_AMP + (b * NV + tid) * 2 + 0];
        float a1 = ws[WS_AMP + (b * NV + tid) * 2 + 1];
#pragma unroll
        for (int off = 32; off > 0; off >>= 1) {
            a0 += __shfl_down(a0, off);
            a1 += __shfl_down(a1, off);
        }
        if (tid == 0) {
            a0 *= (1.0f / NV); a1 *= (1.0f / NV);
            float m = fmaxf(a0, a1);
            float e0v = expf(a0 - m), e1v = expf(a1 - m);
            float inv = 1.0f / (e0v + e1v);
            pwsh[0] = e0v * inv;
            pwsh[1] = e1v * inv;
        }
    }
    int f = br ? f2p[0] : f1p[0];
    float* ob = br ? outb : (ws + WS_OB);
    int rowbase = (bn * DMD + e0) * DMD;
    __syncthreads();
    float pwv = pwsh[br];

    int P = DMD / f;
    int pn = (DMD + P - 1) / P;
    int r = DMD - (pn - 1) * P;
    int Prows = (DMD + pn - 1) / pn;

    if (P == DMD) {
        attn_rank1(pwv, Vsh, xs, ob, rowbase, tid);
        return;
    }
    if (tid < P) {
        float s = 0.f;
        for (int p = 0; p < pn - 1; ++p) s += xs[p * P + tid];
        U[tid] = s;
        xt[tid] = (tid < r) ? xs[(pn - 1) * P + tid] : 0.f;
    }
    __syncthreads();

    if (P <= 4)       attn_small<4>(P, pn, r, Prows, pwv, Vsh, xs, U, xt, W, ob, rowbase, tid);
    else if (P <= 8)  attn_small<8>(P, pn, r, Prows, pwv, Vsh, xs, U, xt, W, ob, rowbase, tid);
    else if (P <= 16) attn_small<16>(P, pn, r, Prows, pwv, Vsh, xs, U, xt, W, ob, rowbase, tid);
    else if (P == 64) attn_pow2<64, 2, 2>(pwv, Vsh, xs, ob, rowbase, tid);
    else if (P == 32) attn_pow2<32, 4, 4>(pwv, Vsh, xs, ob, rowbase, tid);
    else if (P > 32)  attn_midA<16, 4>(P, pn, r, Prows, pwv, Vsh, xs, U, xt, ob, rowbase, tid);  // P=42
    else              attn_midA<8, 8>(P, pn, r, Prows, pwv, Vsh, xs, U, xt, ob, rowbase, tid);   // 18,21,25
}

// ---------------- out[bn][e][h] = sum_m (ob0+ob1)[bn][e][m]*Wo[h][m] + bo[h] ----------------
__global__ __launch_bounds__(256) void k_out(const float* __restrict__ Wo,
                                             const float* __restrict__ bo,
                                             const float* __restrict__ ws,
                                             float* __restrict__ out) {
    int blk = blockIdx.x;          // 256 = 64 bn-pairs * 4 e-quarters
    int bn0 = (blk >> 2) * 2;
    int e0  = (blk & 3) * 32;
    int tid = threadIdx.x;
    __shared__ __align__(16) float WTc[32 * 132];    // [mm][h]
    __shared__ __align__(16) float oT[2][32][36];    // [bnl][mm][e]
    int hg = tid & 31, eg = tid >> 5, h0 = hg * 4;

    float acc[2][4][4];
#pragma unroll
    for (int a = 0; a < 2; ++a)
#pragma unroll
        for (int c = 0; c < 4; ++c)
#pragma unroll
            for (int d = 0; d < 4; ++d) acc[a][c][d] = 0.f;

    for (int mc = 0; mc < 4; ++mc) {
        int m0 = mc * 32;
        __syncthreads();
        for (int idx = tid; idx < 4096; idx += 256) {
            int h = idx >> 5, mm = idx & 31;
            WTc[mm * 132 + h] = Wo[h * DMD + m0 + mm];
        }
        for (int idx = tid; idx < 2048; idx += 256) {
            int bnl = idx >> 10, rem = idx & 1023, e = rem >> 5, mm = rem & 31;
            int gi = ((bn0 + bnl) * DMD + e0 + e) * DMD + m0 + mm;
            oT[bnl][mm][e] = ws[WS_OB + gi] + out[gi];
        }
        __syncthreads();
#pragma unroll 4
        for (int mm = 0; mm < 32; ++mm) {
            const float4 wv = *reinterpret_cast<const float4*>(&WTc[mm * 132 + h0]);
            const float4 q0 = *reinterpret_cast<const float4*>(&oT[0][mm][eg * 4]);
            const float4 q1 = *reinterpret_cast<const float4*>(&oT[1][mm][eg * 4]);
            float ae[2][4] = {{q0.x, q0.y, q0.z, q0.w}, {q1.x, q1.y, q1.z, q1.w}};
#pragma unroll
            for (int bnl = 0; bnl < 2; ++bnl) {
#pragma unroll
                for (int el = 0; el < 4; ++el) {
                    float a = ae[bnl][el];
                    acc[bnl][el][0] = fmaf(a, wv.x, acc[bnl][el][0]);
                    acc[bnl][el][1] = fmaf(a, wv.y, acc[bnl][el][1]);
                    acc[bnl][el][2] = fmaf(a, wv.z, acc[bnl][el][2]);
                    acc[bnl][el][3] = fmaf(a, wv.w, acc[bnl][el][3]);
                }
            }
        }
    }
    const float4 bov = *reinterpret_cast<const float4*>(&bo[h0]);
#pragma unroll
    for (int bnl = 0; bnl < 2; ++bnl) {
#pragma unroll
        for (int el = 0; el < 4; ++el) {
            float4 res = { acc[bnl][el][0] + bov.x, acc[bnl][el][1] + bov.y,
                           acc[bnl][el][2] + bov.z, acc[bnl][el][3] + bov.w };
            int e = e0 + eg * 4 + el;
            *reinterpret_cast<float4*>(&out[((bn0 + bnl) * DMD + e) * DMD + h0]) = res;
        }
    }
}

extern "C" void kernel_launch(void* const* d_in, const int* in_sizes, int n_in,
                              void* d_out, int out_size, void* d_ws, size_t ws_size,
                              hipStream_t stream) {
    const float* x       = (const float*)d_in[0];
    const float* W_emb   = (const float*)d_in[1];
    const float* b_emb   = (const float*)d_in[2];
    const float* W_start = (const float*)d_in[3];
    const float* b_start = (const float*)d_in[4];
    const float* Wel     = (const float*)d_in[5];
    const float* bel     = (const float*)d_in[6];
    const float* Wq      = (const float*)d_in[7];
    const float* bq      = (const float*)d_in[8];
    const float* Wk      = (const float*)d_in[9];
    const float* bk      = (const float*)d_in[10];
    const float* Wv      = (const float*)d_in[11];
    const float* bv      = (const float*)d_in[12];
    const float* Wo      = (const float*)d_in[13];
    const float* bo      = (const float*)d_in[14];
    const int*   f1p     = (const int*)d_in[15];
    const int*   f2p     = (const int*)d_in[16];
    float* ws  = (float*)d_ws;
    float* out = (float*)d_out;

    k_xe<<<33, 512, 0, stream>>>(x, W_emb, b_emb, f1p, f2p,
                                 Wel, bel, W_start, b_start,
                                 Wq, bq, Wk, bk, Wv, bv, ws);
    k_attn<<<dim3(32, NBN, 2), 128, 0, stream>>>(f1p, f2p, ws, out);
    k_out<<<256, 256, 0, stream>>>(Wo, bo, ws, out);
}

// Round 9
// 81.006 us; speedup vs baseline: 1.1611x; 1.0520x over previous
//
#include <hip/hip_runtime.h>

#define DMD 128
#define NV 64
#define BB 2
#define SQ 512
#define NBN 128                 // BB*NV
#define ASCALE 0.08838834764831845f   // 128^-0.5
#define L2E 1.4426950408889634f
#define CSC (ASCALE * L2E)

// workspace layout (float offsets)
#define WS_XE  0                       // [NBN][DMD]
#define WS_VEC (WS_XE + NBN*DMD)       // 9*128
#define WS_OB  (WS_VEC + 9*DMD)        // [NBN][DMD][DMD] branch-0 UNWEIGHTED output
#define WS_AMP (WS_OB + NBN*DMD*DMD)   // [BB][NV][2] DFT magnitudes
// branch-1 unweighted output lives in d_out (read then overwritten by k_out)

// ---------------- xe + per-(b,n) DFT mags (blocks 0-127) + rank-1 vectors (block 128) ----------
__global__ __launch_bounds__(512) void k_xe(const float* __restrict__ x,
                                            const float* __restrict__ W_emb,
                                            const float* __restrict__ b_emb,
                                            const int* __restrict__ f1p,
                                            const int* __restrict__ f2p,
                                            const float* __restrict__ Wel, const float* __restrict__ bel,
                                            const float* __restrict__ W_start, const float* __restrict__ b_start,
                                            const float* __restrict__ Wq, const float* __restrict__ bq,
                                            const float* __restrict__ Wk, const float* __restrict__ bk,
                                            const float* __restrict__ Wv, const float* __restrict__ bv,
                                            float* __restrict__ ws) {
    int blk = blockIdx.x;
    int tid = threadIdx.x;
    __shared__ float xsh[SQ];
    __shared__ float part[3][DMD];
    __shared__ float red[2][4];
    __shared__ __align__(16) float A[DMD], C[DMD], BL[DMD];

    if (blk < NBN) {
        int bn = blk, b = bn >> 6, n = bn & 63;
        int t = tid & 127, sc = tid >> 7;
        xsh[tid] = x[(b * SQ + tid) * NV + n];
        __syncthreads();
        float acc = 0.f;
        const float* W = W_emb + (sc * 128) * DMD + t;
#pragma unroll 8
        for (int s = 0; s < 128; ++s) acc = fmaf(xsh[sc * 128 + s], W[s * DMD], acc);
        if (sc) part[sc - 1][t] = acc;
        __syncthreads();
        if (sc == 0) {
            float r = acc + part[0][t] + part[1][t] + part[2][t] + b_emb[t];
            ws[WS_XE + bn * DMD + t] = r;
            // DFT at f1,f2 over t
            int f1v = f1p[0], f2v = f2p[0];
            float angA = (float)((f1v * t) & 127) * 0.04908738521234052f;
            float angB = (float)((f2v * t) & 127) * 0.04908738521234052f;
            float v0 = r * cosf(angA), v1 = r * sinf(angA);
            float v2 = r * cosf(angB), v3 = r * sinf(angB);
#pragma unroll
            for (int off = 32; off > 0; off >>= 1) {
                v0 += __shfl_xor(v0, off); v1 += __shfl_xor(v1, off);
                v2 += __shfl_xor(v2, off); v3 += __shfl_xor(v3, off);
            }
            if ((tid & 63) == 0) {
                int w = tid >> 6;
                red[w][0] = v0; red[w][1] = v1; red[w][2] = v2; red[w][3] = v3;
            }
        }
        __syncthreads();
        if (tid == 0) {
            float re0 = red[0][0] + red[1][0], im0 = red[0][1] + red[1][1];
            float re1 = red[0][2] + red[1][2], im1 = red[0][3] + red[1][3];
            ws[WS_AMP + bn * 2 + 0] = sqrtf(re0 * re0 + im0 * im0);
            ws[WS_AMP + bn * 2 + 1] = sqrtf(re1 * re1 + im1 * im1);
        }
    } else {
        // ---- rank-1 projected vectors (weights only) ----
        int e = tid;
        if (tid < 128) {
            float a = 0.f, c = 0.f;
            const float4* We4 = reinterpret_cast<const float4*>(Wel + e * DMD);
            const float4* Ws4 = reinterpret_cast<const float4*>(W_start);
            const float4* Bs4 = reinterpret_cast<const float4*>(b_start);
#pragma unroll 8
            for (int d4 = 0; d4 < 32; ++d4) {
                float4 w = We4[d4], s4 = Ws4[d4], t4 = Bs4[d4];
                a = fmaf(w.x, s4.x, fmaf(w.y, s4.y, fmaf(w.z, s4.z, fmaf(w.w, s4.w, a))));
                c = fmaf(w.x, t4.x, fmaf(w.y, t4.y, fmaf(w.z, t4.z, fmaf(w.w, t4.w, c))));
            }
            A[e] = a;
            C[e] = c + bel[e];
            BL[e] = bel[e];
        }
        __syncthreads();
        if (tid < 128) {
            float aq = 0, cq = 0, pq = 0, ak = 0, ck = 0, pk = 0, av = 0, cv = 0, pv = 0;
            const float4* Wq4 = reinterpret_cast<const float4*>(Wq + e * DMD);
            const float4* Wk4 = reinterpret_cast<const float4*>(Wk + e * DMD);
            const float4* Wv4 = reinterpret_cast<const float4*>(Wv + e * DMD);
            const float4* A4 = reinterpret_cast<const float4*>(A);
            const float4* C4 = reinterpret_cast<const float4*>(C);
            const float4* B4 = reinterpret_cast<const float4*>(BL);
#pragma unroll 4
            for (int d4 = 0; d4 < 32; ++d4) {
                float4 Ad = A4[d4], Cd = C4[d4], Bd = B4[d4];
                float4 wq = Wq4[d4], wk = Wk4[d4], wv = Wv4[d4];
                aq = fmaf(wq.x, Ad.x, fmaf(wq.y, Ad.y, fmaf(wq.z, Ad.z, fmaf(wq.w, Ad.w, aq))));
                cq = fmaf(wq.x, Cd.x, fmaf(wq.y, Cd.y, fmaf(wq.z, Cd.z, fmaf(wq.w, Cd.w, cq))));
                pq = fmaf(wq.x, Bd.x, fmaf(wq.y, Bd.y, fmaf(wq.z, Bd.z, fmaf(wq.w, Bd.w, pq))));
                ak = fmaf(wk.x, Ad.x, fmaf(wk.y, Ad.y, fmaf(wk.z, Ad.z, fmaf(wk.w, Ad.w, ak))));
                ck = fmaf(wk.x, Cd.x, fmaf(wk.y, Cd.y, fmaf(wk.z, Cd.z, fmaf(wk.w, Cd.w, ck))));
                pk = fmaf(wk.x, Bd.x, fmaf(wk.y, Bd.y, fmaf(wk.z, Bd.z, fmaf(wk.w, Bd.w, pk))));
                av = fmaf(wv.x, Ad.x, fmaf(wv.y, Ad.y, fmaf(wv.z, Ad.z, fmaf(wv.w, Ad.w, av))));
                cv = fmaf(wv.x, Cd.x, fmaf(wv.y, Cd.y, fmaf(wv.z, Cd.z, fmaf(wv.w, Cd.w, cv))));
                pv = fmaf(wv.x, Bd.x, fmaf(wv.y, Bd.y, fmaf(wv.z, Bd.z, fmaf(wv.w, Bd.w, pv))));
            }
            float* V = ws + WS_VEC;
            V[0 * DMD + e] = aq; V[1 * DMD + e] = cq + bq[e]; V[2 * DMD + e] = pq + bq[e];
            V[3 * DMD + e] = ak; V[4 * DMD + e] = ck + bk[e]; V[5 * DMD + e] = pk + bk[e];
            V[6 * DMD + e] = av; V[7 * DMD + e] = cv + bv[e]; V[8 * DMD + e] = pv + bv[e];
        }
    }
}

// ============ attention paths (4 e's per block, single branch, unweighted direct stores) =======

// Rank-1: P == 128 (f == 1)
__device__ __forceinline__ void attn_rank1(const float (*Vsh)[4],
                                           const float* xs, float* __restrict__ ob,
                                           int rowbase, int tid) {
    float xi = xs[tid];
    float t[4], l[4], ax[4];
#pragma unroll
    for (int k = 0; k < 4; ++k) {
        float Aq = Vsh[0][k], Cq = Vsh[1][k], Ak = Vsh[3][k];
        t[k] = CSC * fmaf(xi, Aq, Cq) * Ak;
        l[k] = 0.f; ax[k] = 0.f;
    }
#pragma unroll 4
    for (int j = 0; j < DMD; ++j) {
        float xj = xs[j];
#pragma unroll
        for (int k = 0; k < 4; ++k) {
            float ev = exp2f(t[k] * xj);
            l[k] += ev;
            ax[k] = fmaf(ev, xj, ax[k]);
        }
    }
#pragma unroll
    for (int k = 0; k < 4; ++k) {
        float Av = Vsh[6][k], Cv = Vsh[7][k];
        ob[rowbase + k * DMD + tid] = fmaf(Av, ax[k] / l[k], Cv);
    }
}

// pow2-P path: P in {32,64}, no padding; EB e's batched per pass
template<int PP, int NP, int EB>
__device__ __forceinline__ void attn_pow2(const float (*Vsh)[4],
                                          const float* xs, float* __restrict__ ob,
                                          int rowbase, int tid) {
    const int UH = PP / 4;
    int lane4 = tid & 3, i0 = tid >> 2, jb = lane4 * UH;

    float xq[NP][UH], U2[UH];
#pragma unroll
    for (int u = 0; u < UH; ++u) {
        int j = jb + u;
        float s = 0.f;
#pragma unroll
        for (int q = 0; q < NP; ++q) { float xv = xs[q * PP + j]; xq[q][u] = xv; s += xv; }
        U2[u] = s;
    }
    const int NREP = (PP == 64) ? 2 : 1;
#pragma unroll
    for (int rep = 0; rep < NREP; ++rep) {
        int i = i0 + rep * 32;
        float G2[UH];
#pragma unroll
        for (int u = 0; u < UH; ++u) G2[u] = 0.f;
#pragma unroll
        for (int q = 0; q < NP; ++q) {
            float xi = xs[q * PP + i];
#pragma unroll
            for (int u = 0; u < UH; ++u) G2[u] = fmaf(xi, xq[q][u], G2[u]);
        }
#pragma unroll
        for (int eg = 0; eg < 4; eg += EB) {
            float d1[EB], d2[EB], l[EB];
            float accq[NP][EB];
#pragma unroll
            for (int k = 0; k < EB; ++k) {
                float t = CSC * Vsh[3][eg + k];
                d1[k] = t * Vsh[0][eg + k];
                d2[k] = t * Vsh[1][eg + k];
                l[k] = 0.f;
#pragma unroll
                for (int q = 0; q < NP; ++q) accq[q][k] = 0.f;
            }
#pragma unroll
            for (int u = 0; u < UH; ++u) {
                float gg = G2[u], uu = U2[u];
                float ev[EB];
#pragma unroll
                for (int k = 0; k < EB; ++k) ev[k] = exp2f(fmaf(d1[k], gg, d2[k] * uu));
#pragma unroll
                for (int k = 0; k < EB; ++k) {
                    l[k] += ev[k];
#pragma unroll
                    for (int q = 0; q < NP; ++q) accq[q][k] = fmaf(ev[k], xq[q][u], accq[q][k]);
                }
            }
#pragma unroll
            for (int k = 0; k < EB; ++k) { l[k] += __shfl_xor(l[k], 1); l[k] += __shfl_xor(l[k], 2); }
#pragma unroll
            for (int q = 0; q < NP; ++q)
#pragma unroll
                for (int k = 0; k < EB; ++k) {
                    accq[q][k] += __shfl_xor(accq[q][k], 1);
                    accq[q][k] += __shfl_xor(accq[q][k], 2);
                }
            if (lane4 == 0) {
#pragma unroll
                for (int k = 0; k < EB; ++k) {
                    float li = 1.f / l[k];
                    float Av = Vsh[6][eg + k], Cv = Vsh[7][eg + k];
#pragma unroll
                    for (int q = 0; q < NP; ++q) {
                        ob[rowbase + (eg + k) * DMD + i * NP + q] = fmaf(Av, accq[q][k] * li, Cv);
                    }
                }
            }
        }
    }
}

// small-P path: P <= 16. Scores for all 4 e's computed once (2 slots/thread) -> LDS W,
// single barrier, PV thread-per-output.
template<int UB>
__device__ __forceinline__ void attn_small(
    int P, int pn, int r, int Prows,
    const float (*Vsh)[4], const float* xs, const float* U, const float* xt,
    float* W, float* __restrict__ ob, int rowbase, int tid)
{
    int GP = P + 1;
    int tot = Prows * P;
    unsigned mP = (4096u + (unsigned)P - 1u) / (unsigned)P;     // ceil(4096/P)
    unsigned mpn = (4096u + (unsigned)pn - 1u) / (unsigned)pn;  // ceil(4096/pn)

    // ---- slot 0 (score idx = tid) ----
    bool v0 = (tid < tot);
    int i0 = (int)(((unsigned)tid * mP) >> 12);
    int j0 = tid - i0 * P;
    bool A0 = (i0 < r), c0 = (j0 < r);
    float xtj0 = xt[j0], Uj0 = U[j0];
    float xti0 = A0 ? xt[i0] : 0.f;
    float g0 = 0.f;
    for (int p = 0; p < pn - 1; ++p) g0 = fmaf(xs[p * P + i0], xs[p * P + j0], g0);
    float Gx0 = (A0 && c0) ? fmaf(xti0, xtj0, g0) : g0;
    float Ux0 = (A0 && c0) ? Uj0 + xtj0 : Uj0;
    float Xw0 = (!A0 && c0) ? xtj0 : 0.f;
    float mw0 = c0 ? 1.f : 0.f;
    int wa0 = i0 * GP + j0;

    // ---- slot 1 (score idx = tid + 128) ----
    int idx1 = tid + 128;
    bool v1 = (idx1 < tot);
    int idx1c = v1 ? idx1 : 0;
    int i1 = (int)(((unsigned)idx1c * mP) >> 12);
    int j1 = idx1c - i1 * P;
    bool A1 = (i1 < r), c1 = (j1 < r);
    float xtj1 = xt[j1], Uj1 = U[j1];
    float xti1 = A1 ? xt[i1] : 0.f;
    float g1 = 0.f;
    for (int p = 0; p < pn - 1; ++p) g1 = fmaf(xs[p * P + i1], xs[p * P + j1], g1);
    float Gx1 = (A1 && c1) ? fmaf(xti1, xtj1, g1) : g1;
    float Ux1 = (A1 && c1) ? Uj1 + xtj1 : Uj1;
    float Xw1 = (!A1 && c1) ? xtj1 : 0.f;
    float mw1 = c1 ? 1.f : 0.f;
    int wa1 = i1 * GP + j1;

    // ---- PV assignment: output mo = tid -> (i2, p2) ----
    int i2 = (int)(((unsigned)tid * mpn) >> 12);
    int p2 = tid - i2 * pn;
    bool lastp = (p2 == pn - 1);
    int row2 = i2 * GP;
    float xsr[UB];
#pragma unroll
    for (int j = 0; j < UB; ++j) {
        int idx = p2 * P + j;
        xsr[j] = (j < P && idx < DMD) ? xs[idx] : 0.f;
    }

    // ---- score phase: 8 exps batched, one barrier ----
    float s[4][2];
#pragma unroll
    for (int ec = 0; ec < 4; ++ec) {
        float Aq = Vsh[0][ec], Cq = Vsh[1][ec], Pq = Vsh[2][ec];
        float Ak = Vsh[3][ec], Ck = Vsh[4][ec], Pk = Vsh[5][ec];
        float t = CSC * Ak;
        float d1 = t * Aq, d2 = t * Cq, d3 = t * Pq;
        float ckpk = CSC * (Ck - Pk);
        float aS0 = A0 ? fmaf(Aq, xti0, Cq) : Pq;
        s[ec][0] = fmaf(d1, Gx0, fmaf(d2, Ux0, fmaf(d3, Xw0, (ckpk * aS0) * mw0)));
        float aS1 = A1 ? fmaf(Aq, xti1, Cq) : Pq;
        s[ec][1] = fmaf(d1, Gx1, fmaf(d2, Ux1, fmaf(d3, Xw1, (ckpk * aS1) * mw1)));
    }
#pragma unroll
    for (int ec = 0; ec < 4; ++ec) { s[ec][0] = exp2f(s[ec][0]); s[ec][1] = exp2f(s[ec][1]); }
#pragma unroll
    for (int ec = 0; ec < 4; ++ec) {
        if (v0) W[ec * 288 + wa0] = s[ec][0];
        if (v1) W[ec * 288 + wa1] = s[ec][1];
    }
    __syncthreads();

    // ---- PV phase ----
#pragma unroll
    for (int ec = 0; ec < 4; ++ec) {
        float Av = Vsh[6][ec], Cv = Vsh[7][ec], Pv = Vsh[8][ec];
        float l = 0.f, wr = 0.f, ax = 0.f;
#pragma unroll
        for (int j = 0; j < UB; ++j) {
            float w = W[ec * 288 + row2 + ((j < P) ? j : 0)];
            w = (j < P) ? w : 0.f;
            l += w;
            wr += (j < r) ? w : 0.f;
            ax = fmaf(w, xsr[j], ax);
        }
        float li = 1.f / l;
        float o;
        if (lastp) { float sl = wr * li; o = fmaf(Av, ax * li, fmaf(Cv, sl, Pv * (1.f - sl))); }
        else       o = fmaf(Av, ax * li, Cv);
        ob[rowbase + ec * DMD + tid] = o;
    }
}

// mid-P path (P in {18,21,25,42}): register scheme with masks
template<int UH, int NP>
__device__ __forceinline__ void attn_midA(
    int P, int pn, int r, int Prows,
    const float (*Vsh)[4], const float* xs, const float* U,
    const float* xt, float* __restrict__ ob, int rowbase, int tid)
{
    int lane4 = tid & 3;
    int i0 = tid >> 2;
    int jb = lane4 * UH;

    float Ur[UH], xtr[UH], xq0[UH], xq1[UH];
#pragma unroll
    for (int u = 0; u < UH; ++u) {
        int j = jb + u, jc = (j < P) ? j : 0;
        Ur[u] = U[jc];
        xtr[u] = xt[jc];
        xq0[u] = (j < DMD) ? xs[j] : 0.f;
        int i1x = P + j;
        xq1[u] = (i1x < DMD) ? xs[i1x] : 0.f;
    }
    int nrep = (Prows > 32) ? 2 : 1;
    for (int rep = 0; rep < nrep; ++rep) {
        int i = i0 + rep * 32;
        bool rowact = (i < Prows);
        int ic = rowact ? i : 0;
        float xtic = xt[ic];
        bool rowvalid = (ic < r);
        float g[UH];
#pragma unroll
        for (int u = 0; u < UH; ++u) g[u] = 0.f;
        for (int p = 0; p < pn - 1; ++p) {
            float xi = xs[p * P + ic];
#pragma unroll
            for (int u = 0; u < UH; ++u) {
                int j = jb + u, jc = (j < P) ? j : 0;
                g[u] = fmaf(xi, xs[p * P + jc], g[u]);
            }
        }
        for (int ec = 0; ec < 4; ++ec) {
            float Aq = Vsh[0][ec], Cq = Vsh[1][ec], Pq = Vsh[2][ec];
            float Ak = Vsh[3][ec], Ck = Vsh[4][ec], Pk = Vsh[5][ec];
            float Av = Vsh[6][ec], Cv = Vsh[7][ec], Pv = Vsh[8][ec];
            float c1 = CSC * Aq * Ak, c3 = CSC * Cq * Ak;
            float asi = CSC * (rowvalid ? fmaf(xtic, Aq, Cq) : Pq);

            float l0 = 0.f, l1 = 0.f, w0 = 0.f, w1 = 0.f;
            float accq[NP];
#pragma unroll
            for (int q = 0; q < NP; ++q) accq[q] = 0.f;
#pragma unroll
            for (int u = 0; u < UH; ++u) {
                int j = jb + u;
                float bK = (j < r) ? fmaf(xtr[u], Ak, Ck) : Pk;
                float S = fmaf(asi, bK, fmaf(c3, Ur[u], c1 * g[u]));
                float ev = exp2f(S);
                ev = (j < P) ? ev : 0.f;
                if (u & 1) l1 += ev; else l0 += ev;
                float evr = (j < r) ? ev : 0.f;
                if (u & 1) w1 += evr; else w0 += evr;
                accq[0] = fmaf(ev, xq0[u], accq[0]);
                if (NP >= 2) accq[1] = fmaf(ev, xq1[u], accq[1]);
#pragma unroll
                for (int q = 2; q < NP; ++q) {
                    int idx = q * P + j;
                    float xv = (idx < DMD) ? xs[idx] : 0.f;
                    accq[q] = fmaf(ev, xv, accq[q]);
                }
            }
            float l = l0 + l1, wr = w0 + w1;
            l += __shfl_xor(l, 1);  l += __shfl_xor(l, 2);
            wr += __shfl_xor(wr, 1); wr += __shfl_xor(wr, 2);
#pragma unroll
            for (int q = 0; q < NP; ++q) {
                if (q < pn) {
                    accq[q] += __shfl_xor(accq[q], 1);
                    accq[q] += __shfl_xor(accq[q], 2);
                }
            }
            if (lane4 == 0 && rowact) {
                float li = 1.f / l;
#pragma unroll
                for (int q = 0; q < NP; ++q) {
                    if (q < pn) {
                        int mo = i * pn + q;
                        if (mo < DMD) {
                            float o;
                            if (q == pn - 1) {
                                float sl = wr * li;
                                o = fmaf(Av, accq[q] * li, fmaf(Cv, sl, Pv * (1.f - sl)));
                            } else {
                                o = fmaf(Av, accq[q] * li, Cv);
                            }
                            ob[rowbase + ec * DMD + mo] = o;
                        }
                    }
                }
            }
        }
    }
}

__global__ __launch_bounds__(128) void k_attn(const int* __restrict__ f1p,
                                              const int* __restrict__ f2p,
                                              float* __restrict__ ws,
                                              float* __restrict__ outb) {
    int bn = blockIdx.y;
    int e0 = blockIdx.x * 4;           // 32 chunks of 4 e's
    int br = blockIdx.z;
    int tid = threadIdx.x;

    __shared__ float xs[DMD], U[64], xt[64];
    __shared__ float Vsh[9][4];
    __shared__ float W[4 * 288];

    xs[tid] = ws[WS_XE + bn * DMD + tid];
    if (tid < 36) Vsh[tid >> 2][tid & 3] = ws[WS_VEC + (tid >> 2) * DMD + e0 + (tid & 3)];
    int f = br ? f2p[0] : f1p[0];
    float* ob = br ? outb : (ws + WS_OB);
    int rowbase = (bn * DMD + e0) * DMD;
    __syncthreads();

    int P = DMD / f;
    int pn = (DMD + P - 1) / P;
    int r = DMD - (pn - 1) * P;
    int Prows = (DMD + pn - 1) / pn;

    if (P == DMD) {
        attn_rank1(Vsh, xs, ob, rowbase, tid);
        return;
    }
    if (tid < P) {
        float s = 0.f;
        for (int p = 0; p < pn - 1; ++p) s += xs[p * P + tid];
        U[tid] = s;
        xt[tid] = (tid < r) ? xs[(pn - 1) * P + tid] : 0.f;
    }
    __syncthreads();

    if (P <= 4)       attn_small<4>(P, pn, r, Prows, Vsh, xs, U, xt, W, ob, rowbase, tid);
    else if (P <= 8)  attn_small<8>(P, pn, r, Prows, Vsh, xs, U, xt, W, ob, rowbase, tid);
    else if (P <= 16) attn_small<16>(P, pn, r, Prows, Vsh, xs, U, xt, W, ob, rowbase, tid);
    else if (P == 64) attn_pow2<64, 2, 2>(Vsh, xs, ob, rowbase, tid);
    else if (P == 32) attn_pow2<32, 4, 4>(Vsh, xs, ob, rowbase, tid);
    else if (P > 32)  attn_midA<16, 4>(P, pn, r, Prows, Vsh, xs, U, xt, ob, rowbase, tid);  // P=42
    else              attn_midA<8, 8>(P, pn, r, Prows, Vsh, xs, U, xt, ob, rowbase, tid);   // 18,21,25
}

// ---------------- out[bn][e][h] = sum_m (pw0*ob0+pw1*ob1)[bn][e][m]*Wo[h][m] + bo[h] ----------
__global__ __launch_bounds__(256) void k_out(const float* __restrict__ Wo,
                                             const float* __restrict__ bo,
                                             const float* __restrict__ ws,
                                             float* __restrict__ out) {
    int blk = blockIdx.x;          // 256 = 64 bn-pairs * 4 e-quarters
    int bn0 = (blk >> 2) * 2;
    int e0  = (blk & 3) * 32;
    int b = bn0 >> 6;
    int tid = threadIdx.x;
    __shared__ __align__(16) float WTc[32 * 132];    // [mm][h]
    __shared__ __align__(16) float oT[2][32][36];    // [bnl][mm][e]
    __shared__ float pwsh[2];
    int hg = tid & 31, eg = tid >> 5, h0 = hg * 4;

    // period weights from DFT magnitudes (64-lane reduce, wave 0)
    if (tid < 64) {
        float a0 = ws[WS_AMP + (b * NV + tid) * 2 + 0];
        float a1 = ws[WS_AMP + (b * NV + tid) * 2 + 1];
#pragma unroll
        for (int off = 32; off > 0; off >>= 1) {
            a0 += __shfl_down(a0, off);
            a1 += __shfl_down(a1, off);
        }
        if (tid == 0) {
            a0 *= (1.0f / NV); a1 *= (1.0f / NV);
            float m = fmaxf(a0, a1);
            float e0v = expf(a0 - m), e1v = expf(a1 - m);
            float inv = 1.0f / (e0v + e1v);
            pwsh[0] = e0v * inv;
            pwsh[1] = e1v * inv;
        }
    }
    __syncthreads();
    float pw0 = pwsh[0], pw1 = pwsh[1];

    float acc[2][4][4];
#pragma unroll
    for (int a = 0; a < 2; ++a)
#pragma unroll
        for (int c = 0; c < 4; ++c)
#pragma unroll
            for (int d = 0; d < 4; ++d) acc[a][c][d] = 0.f;

    for (int mc = 0; mc < 4; ++mc) {
        int m0 = mc * 32;
        __syncthreads();
        for (int idx = tid; idx < 4096; idx += 256) {
            int h = idx >> 5, mm = idx & 31;
            WTc[mm * 132 + h] = Wo[h * DMD + m0 + mm];
        }
        for (int idx = tid; idx < 2048; idx += 256) {
            int bnl = idx >> 10, rem = idx & 1023, e = rem >> 5, mm = rem & 31;
            int gi = ((bn0 + bnl) * DMD + e0 + e) * DMD + m0 + mm;
            oT[bnl][mm][e] = fmaf(pw0, ws[WS_OB + gi], pw1 * out[gi]);
        }
        __syncthreads();
#pragma unroll 4
        for (int mm = 0; mm < 32; ++mm) {
            const float4 wv = *reinterpret_cast<const float4*>(&WTc[mm * 132 + h0]);
            const float4 q0 = *reinterpret_cast<const float4*>(&oT[0][mm][eg * 4]);
            const float4 q1 = *reinterpret_cast<const float4*>(&oT[1][mm][eg * 4]);
            float ae[2][4] = {{q0.x, q0.y, q0.z, q0.w}, {q1.x, q1.y, q1.z, q1.w}};
#pragma unroll
            for (int bnl = 0; bnl < 2; ++bnl) {
#pragma unroll
                for (int el = 0; el < 4; ++el) {
                    float a = ae[bnl][el];
                    acc[bnl][el][0] = fmaf(a, wv.x, acc[bnl][el][0]);
                    acc[bnl][el][1] = fmaf(a, wv.y, acc[bnl][el][1]);
                    acc[bnl][el][2] = fmaf(a, wv.z, acc[bnl][el][2]);
                    acc[bnl][el][3] = fmaf(a, wv.w, acc[bnl][el][3]);
                }
            }
        }
    }
    const float4 bov = *reinterpret_cast<const float4*>(&bo[h0]);
#pragma unroll
    for (int bnl = 0; bnl < 2; ++bnl) {
#pragma unroll
        for (int el = 0; el < 4; ++el) {
            float4 res = { acc[bnl][el][0] + bov.x, acc[bnl][el][1] + bov.y,
                           acc[bnl][el][2] + bov.z, acc[bnl][el][3] + bov.w };
            int e = e0 + eg * 4 + el;
            *reinterpret_cast<float4*>(&out[((bn0 + bnl) * DMD + e) * DMD + h0]) = res;
        }
    }
}

extern "C" void kernel_launch(void* const* d_in, const int* in_sizes, int n_in,
                              void* d_out, int out_size, void* d_ws, size_t ws_size,
                              hipStream_t stream) {
    const float* x       = (const float*)d_in[0];
    const float* W_emb   = (const float*)d_in[1];
    const float* b_emb   = (const float*)d_in[2];
    const float* W_start = (const float*)d_in[3];
    const float* b_start = (const float*)d_in[4];
    const float* Wel     = (const float*)d_in[5];
    const float* bel     = (const float*)d_in[6];
    const float* Wq      = (const float*)d_in[7];
    const float* bq      = (const float*)d_in[8];
    const float* Wk      = (const float*)d_in[9];
    const float* bk      = (const float*)d_in[10];
    const float* Wv      = (const float*)d_in[11];
    const float* bv      = (const float*)d_in[12];
    const float* Wo      = (const float*)d_in[13];
    const float* bo      = (const float*)d_in[14];
    const int*   f1p     = (const int*)d_in[15];
    const int*   f2p     = (const int*)d_in[16];
    float* ws  = (float*)d_ws;
    float* out = (float*)d_out;

    k_xe<<<NBN + 1, 512, 0, stream>>>(x, W_emb, b_emb, f1p, f2p,
                                      Wel, bel, W_start, b_start,
                                      Wq, bq, Wk, bk, Wv, bv, ws);
    k_attn<<<dim3(32, NBN, 2), 128, 0, stream>>>(f1p, f2p, ws, out);
    k_out<<<256, 256, 0, stream>>>(Wo, bo, ws, out);
}

// Round 10
// 74.218 us; speedup vs baseline: 1.2673x; 1.0915x over previous
//
#include <hip/hip_runtime.h>

#define DMD 128
#define NV 64
#define BB 2
#define SQ 512
#define NBN 128                 // BB*NV
#define ASCALE 0.08838834764831845f   // 128^-0.5
#define L2E 1.4426950408889634f
#define CSC (ASCALE * L2E)

// workspace layout (float offsets)
#define WS_XE  0                       // [NBN][DMD]
#define WS_VEC (WS_XE + NBN*DMD)       // 9*128
#define WS_OB  (WS_VEC + 9*DMD)        // [NBN][DMD][DMD] branch-0 UNWEIGHTED output
#define WS_AMP (WS_OB + NBN*DMD*DMD)   // [NBN][2] DFT magnitudes
#define WS_G   (WS_AMP + NBN*2)        // [NBN][2][288] small-P Gram (stride P+1)
// branch-1 unweighted output lives in d_out (read then overwritten by k_out)

// ---------------- xe + DFT mags + small-P Gram (blocks 0-127) + rank-1 vectors (block 128) -----
__global__ __launch_bounds__(512) void k_xe(const float* __restrict__ x,
                                            const float* __restrict__ W_emb,
                                            const float* __restrict__ b_emb,
                                            const int* __restrict__ f1p,
                                            const int* __restrict__ f2p,
                                            const float* __restrict__ Wel, const float* __restrict__ bel,
                                            const float* __restrict__ W_start, const float* __restrict__ b_start,
                                            const float* __restrict__ Wq, const float* __restrict__ bq,
                                            const float* __restrict__ Wk, const float* __restrict__ bk,
                                            const float* __restrict__ Wv, const float* __restrict__ bv,
                                            float* __restrict__ ws) {
    int blk = blockIdx.x;
    int tid = threadIdx.x;
    __shared__ float xsh[SQ];
    __shared__ float part[3][DMD];
    __shared__ float red[2][4];
    __shared__ float xe_sh[DMD];
    __shared__ __align__(16) float A[DMD], C[DMD], BL[DMD];

    if (blk < NBN) {
        int bn = blk, b = bn >> 6, n = bn & 63;
        int t = tid & 127, sc = tid >> 7;
        int f1v = f1p[0], f2v = f2p[0];
        xsh[tid] = x[(b * SQ + tid) * NV + n];
        __syncthreads();
        float acc = 0.f;
        const float* W = W_emb + (sc * 128) * DMD + t;
#pragma unroll 8
        for (int s = 0; s < 128; ++s) acc = fmaf(xsh[sc * 128 + s], W[s * DMD], acc);
        if (sc) part[sc - 1][t] = acc;
        __syncthreads();
        if (sc == 0) {
            float r = acc + part[0][t] + part[1][t] + part[2][t] + b_emb[t];
            ws[WS_XE + bn * DMD + t] = r;
            xe_sh[t] = r;
            // DFT at f1,f2 over t
            float angA = (float)((f1v * t) & 127) * 0.04908738521234052f;
            float angB = (float)((f2v * t) & 127) * 0.04908738521234052f;
            float v0 = r * cosf(angA), v1 = r * sinf(angA);
            float v2 = r * cosf(angB), v3 = r * sinf(angB);
#pragma unroll
            for (int off = 32; off > 0; off >>= 1) {
                v0 += __shfl_xor(v0, off); v1 += __shfl_xor(v1, off);
                v2 += __shfl_xor(v2, off); v3 += __shfl_xor(v3, off);
            }
            if ((tid & 63) == 0) {
                int w = tid >> 6;
                red[w][0] = v0; red[w][1] = v1; red[w][2] = v2; red[w][3] = v3;
            }
        }
        __syncthreads();   // xe_sh + red ready
        if (tid == 0) {
            float re0 = red[0][0] + red[1][0], im0 = red[0][1] + red[1][1];
            float re1 = red[0][2] + red[1][2], im1 = red[0][3] + red[1][3];
            ws[WS_AMP + bn * 2 + 0] = sqrtf(re0 * re0 + im0 * im0);
            ws[WS_AMP + bn * 2 + 1] = sqrtf(re1 * re1 + im1 * im1);
        }
        // ---- small-P Gram precompute: branch = tid>>8, entry = tid&255 ----
        {
            int br = tid >> 8;
            int entry = tid & 255;
            int f = br ? f2v : f1v;
            int P = DMD / f;
            if (P <= 16) {
                int pn = (DMD + P - 1) / P;
                int Prows = (DMD + pn - 1) / pn;
                int tot = Prows * P;
                if (entry < tot) {
                    int i = entry / P;
                    int j = entry - i * P;
                    float g = 0.f;
                    for (int p = 0; p < pn - 1; ++p)
                        g = fmaf(xe_sh[p * P + i], xe_sh[p * P + j], g);
                    ws[WS_G + (bn * 2 + br) * 288 + i * (P + 1) + j] = g;
                }
            }
        }
    } else {
        // ---- rank-1 projected vectors (weights only) ----
        int e = tid;
        if (tid < 128) {
            float a = 0.f, c = 0.f;
            const float4* We4 = reinterpret_cast<const float4*>(Wel + e * DMD);
            const float4* Ws4 = reinterpret_cast<const float4*>(W_start);
            const float4* Bs4 = reinterpret_cast<const float4*>(b_start);
#pragma unroll 8
            for (int d4 = 0; d4 < 32; ++d4) {
                float4 w = We4[d4], s4 = Ws4[d4], t4 = Bs4[d4];
                a = fmaf(w.x, s4.x, fmaf(w.y, s4.y, fmaf(w.z, s4.z, fmaf(w.w, s4.w, a))));
                c = fmaf(w.x, t4.x, fmaf(w.y, t4.y, fmaf(w.z, t4.z, fmaf(w.w, t4.w, c))));
            }
            A[e] = a;
            C[e] = c + bel[e];
            BL[e] = bel[e];
        }
        __syncthreads();
        if (tid < 128) {
            float aq = 0, cq = 0, pq = 0, ak = 0, ck = 0, pk = 0, av = 0, cv = 0, pv = 0;
            const float4* Wq4 = reinterpret_cast<const float4*>(Wq + e * DMD);
            const float4* Wk4 = reinterpret_cast<const float4*>(Wk + e * DMD);
            const float4* Wv4 = reinterpret_cast<const float4*>(Wv + e * DMD);
            const float4* A4 = reinterpret_cast<const float4*>(A);
            const float4* C4 = reinterpret_cast<const float4*>(C);
            const float4* B4 = reinterpret_cast<const float4*>(BL);
#pragma unroll 4
            for (int d4 = 0; d4 < 32; ++d4) {
                float4 Ad = A4[d4], Cd = C4[d4], Bd = B4[d4];
                float4 wq = Wq4[d4], wk = Wk4[d4], wv = Wv4[d4];
                aq = fmaf(wq.x, Ad.x, fmaf(wq.y, Ad.y, fmaf(wq.z, Ad.z, fmaf(wq.w, Ad.w, aq))));
                cq = fmaf(wq.x, Cd.x, fmaf(wq.y, Cd.y, fmaf(wq.z, Cd.z, fmaf(wq.w, Cd.w, cq))));
                pq = fmaf(wq.x, Bd.x, fmaf(wq.y, Bd.y, fmaf(wq.z, Bd.z, fmaf(wq.w, Bd.w, pq))));
                ak = fmaf(wk.x, Ad.x, fmaf(wk.y, Ad.y, fmaf(wk.z, Ad.z, fmaf(wk.w, Ad.w, ak))));
                ck = fmaf(wk.x, Cd.x, fmaf(wk.y, Cd.y, fmaf(wk.z, Cd.z, fmaf(wk.w, Cd.w, ck))));
                pk = fmaf(wk.x, Bd.x, fmaf(wk.y, Bd.y, fmaf(wk.z, Bd.z, fmaf(wk.w, Bd.w, pk))));
                av = fmaf(wv.x, Ad.x, fmaf(wv.y, Ad.y, fmaf(wv.z, Ad.z, fmaf(wv.w, Ad.w, av))));
                cv = fmaf(wv.x, Cd.x, fmaf(wv.y, Cd.y, fmaf(wv.z, Cd.z, fmaf(wv.w, Cd.w, cv))));
                pv = fmaf(wv.x, Bd.x, fmaf(wv.y, Bd.y, fmaf(wv.z, Bd.z, fmaf(wv.w, Bd.w, pv))));
            }
            float* V = ws + WS_VEC;
            V[0 * DMD + e] = aq; V[1 * DMD + e] = cq + bq[e]; V[2 * DMD + e] = pq + bq[e];
            V[3 * DMD + e] = ak; V[4 * DMD + e] = ck + bk[e]; V[5 * DMD + e] = pk + bk[e];
            V[6 * DMD + e] = av; V[7 * DMD + e] = cv + bv[e]; V[8 * DMD + e] = pv + bv[e];
        }
    }
}

// ============ attention paths (4 e's per block, single branch, unweighted direct stores) =======

// Rank-1: P == 128 (f == 1)
__device__ __forceinline__ void attn_rank1(const float (*Vsh)[4],
                                           const float* xs, float* __restrict__ ob,
                                           int rowbase, int tid) {
    float xi = xs[tid];
    float t[4], l[4], ax[4];
#pragma unroll
    for (int k = 0; k < 4; ++k) {
        float Aq = Vsh[0][k], Cq = Vsh[1][k], Ak = Vsh[3][k];
        t[k] = CSC * fmaf(xi, Aq, Cq) * Ak;
        l[k] = 0.f; ax[k] = 0.f;
    }
#pragma unroll 4
    for (int j = 0; j < DMD; ++j) {
        float xj = xs[j];
#pragma unroll
        for (int k = 0; k < 4; ++k) {
            float ev = exp2f(t[k] * xj);
            l[k] += ev;
            ax[k] = fmaf(ev, xj, ax[k]);
        }
    }
#pragma unroll
    for (int k = 0; k < 4; ++k) {
        float Av = Vsh[6][k], Cv = Vsh[7][k];
        ob[rowbase + k * DMD + tid] = fmaf(Av, ax[k] / l[k], Cv);
    }
}

// pow2-P path: P in {32,64}, no padding; EB e's batched per pass
template<int PP, int NP, int EB>
__device__ __forceinline__ void attn_pow2(const float (*Vsh)[4],
                                          const float* xs, float* __restrict__ ob,
                                          int rowbase, int tid) {
    const int UH = PP / 4;
    int lane4 = tid & 3, i0 = tid >> 2, jb = lane4 * UH;

    float xq[NP][UH], U2[UH];
#pragma unroll
    for (int u = 0; u < UH; ++u) {
        int j = jb + u;
        float s = 0.f;
#pragma unroll
        for (int q = 0; q < NP; ++q) { float xv = xs[q * PP + j]; xq[q][u] = xv; s += xv; }
        U2[u] = s;
    }
    const int NREP = (PP == 64) ? 2 : 1;
#pragma unroll
    for (int rep = 0; rep < NREP; ++rep) {
        int i = i0 + rep * 32;
        float G2[UH];
#pragma unroll
        for (int u = 0; u < UH; ++u) G2[u] = 0.f;
#pragma unroll
        for (int q = 0; q < NP; ++q) {
            float xi = xs[q * PP + i];
#pragma unroll
            for (int u = 0; u < UH; ++u) G2[u] = fmaf(xi, xq[q][u], G2[u]);
        }
#pragma unroll
        for (int eg = 0; eg < 4; eg += EB) {
            float d1[EB], d2[EB], l[EB];
            float accq[NP][EB];
#pragma unroll
            for (int k = 0; k < EB; ++k) {
                float t = CSC * Vsh[3][eg + k];
                d1[k] = t * Vsh[0][eg + k];
                d2[k] = t * Vsh[1][eg + k];
                l[k] = 0.f;
#pragma unroll
                for (int q = 0; q < NP; ++q) accq[q][k] = 0.f;
            }
#pragma unroll
            for (int u = 0; u < UH; ++u) {
                float gg = G2[u], uu = U2[u];
                float ev[EB];
#pragma unroll
                for (int k = 0; k < EB; ++k) ev[k] = exp2f(fmaf(d1[k], gg, d2[k] * uu));
#pragma unroll
                for (int k = 0; k < EB; ++k) {
                    l[k] += ev[k];
#pragma unroll
                    for (int q = 0; q < NP; ++q) accq[q][k] = fmaf(ev[k], xq[q][u], accq[q][k]);
                }
            }
#pragma unroll
            for (int k = 0; k < EB; ++k) { l[k] += __shfl_xor(l[k], 1); l[k] += __shfl_xor(l[k], 2); }
#pragma unroll
            for (int q = 0; q < NP; ++q)
#pragma unroll
                for (int k = 0; k < EB; ++k) {
                    accq[q][k] += __shfl_xor(accq[q][k], 1);
                    accq[q][k] += __shfl_xor(accq[q][k], 2);
                }
            if (lane4 == 0) {
#pragma unroll
                for (int k = 0; k < EB; ++k) {
                    float li = 1.f / l[k];
                    float Av = Vsh[6][eg + k], Cv = Vsh[7][eg + k];
#pragma unroll
                    for (int q = 0; q < NP; ++q) {
                        ob[rowbase + (eg + k) * DMD + i * NP + q] = fmaf(Av, accq[q][k] * li, Cv);
                    }
                }
            }
        }
    }
}

// small-P path: P <= 16. Gram precomputed per (bn,branch) in k_xe -> 2 global loads.
// Scores for all 4 e's computed once (2 slots/thread) -> LDS W, single barrier, PV per-output.
template<int UB>
__device__ __forceinline__ void attn_small(
    int P, int pn, int r, int Prows,
    const float (*Vsh)[4], const float* xs, const float* U, const float* xt,
    const float* __restrict__ Gb, float* W, float* __restrict__ ob, int rowbase, int tid)
{
    int GP = P + 1;
    int tot = Prows * P;
    unsigned mP = (4096u + (unsigned)P - 1u) / (unsigned)P;     // ceil(4096/P)
    unsigned mpn = (4096u + (unsigned)pn - 1u) / (unsigned)pn;  // ceil(4096/pn)

    // ---- slot 0 (score idx = tid) ----
    bool v0 = (tid < tot);
    int i0 = (int)(((unsigned)tid * mP) >> 12);
    int j0 = tid - i0 * P;
    int wa0 = i0 * GP + j0;
    float g0 = Gb[wa0];                       // precomputed Gram (L2-hot)
    bool A0 = (i0 < r), c0 = (j0 < r);
    float xtj0 = xt[j0], Uj0 = U[j0];
    float xti0 = A0 ? xt[i0] : 0.f;
    float Gx0 = (A0 && c0) ? fmaf(xti0, xtj0, g0) : g0;
    float Ux0 = (A0 && c0) ? Uj0 + xtj0 : Uj0;
    float Xw0 = (!A0 && c0) ? xtj0 : 0.f;
    float mw0 = c0 ? 1.f : 0.f;

    // ---- slot 1 (score idx = tid + 128) ----
    int idx1 = tid + 128;
    bool v1 = (idx1 < tot);
    int idx1c = v1 ? idx1 : 0;
    int i1 = (int)(((unsigned)idx1c * mP) >> 12);
    int j1 = idx1c - i1 * P;
    int wa1 = i1 * GP + j1;
    float g1 = Gb[wa1];
    bool A1 = (i1 < r), c1 = (j1 < r);
    float xtj1 = xt[j1], Uj1 = U[j1];
    float xti1 = A1 ? xt[i1] : 0.f;
    float Gx1 = (A1 && c1) ? fmaf(xti1, xtj1, g1) : g1;
    float Ux1 = (A1 && c1) ? Uj1 + xtj1 : Uj1;
    float Xw1 = (!A1 && c1) ? xtj1 : 0.f;
    float mw1 = c1 ? 1.f : 0.f;

    // ---- PV assignment: output mo = tid -> (i2, p2) ----
    int i2 = (int)(((unsigned)tid * mpn) >> 12);
    int p2 = tid - i2 * pn;
    bool lastp = (p2 == pn - 1);
    int row2 = i2 * GP;
    float xsr[UB];
#pragma unroll
    for (int j = 0; j < UB; ++j) {
        int idx = p2 * P + j;
        xsr[j] = (j < P && idx < DMD) ? xs[idx] : 0.f;
    }

    // ---- score phase: 8 exps batched, one barrier ----
    float s[4][2];
#pragma unroll
    for (int ec = 0; ec < 4; ++ec) {
        float Aq = Vsh[0][ec], Cq = Vsh[1][ec], Pq = Vsh[2][ec];
        float Ak = Vsh[3][ec], Ck = Vsh[4][ec], Pk = Vsh[5][ec];
        float t = CSC * Ak;
        float d1 = t * Aq, d2 = t * Cq, d3 = t * Pq;
        float ckpk = CSC * (Ck - Pk);
        float aS0 = A0 ? fmaf(Aq, xti0, Cq) : Pq;
        s[ec][0] = fmaf(d1, Gx0, fmaf(d2, Ux0, fmaf(d3, Xw0, (ckpk * aS0) * mw0)));
        float aS1 = A1 ? fmaf(Aq, xti1, Cq) : Pq;
        s[ec][1] = fmaf(d1, Gx1, fmaf(d2, Ux1, fmaf(d3, Xw1, (ckpk * aS1) * mw1)));
    }
#pragma unroll
    for (int ec = 0; ec < 4; ++ec) { s[ec][0] = exp2f(s[ec][0]); s[ec][1] = exp2f(s[ec][1]); }
#pragma unroll
    for (int ec = 0; ec < 4; ++ec) {
        if (v0) W[ec * 288 + wa0] = s[ec][0];
        if (v1) W[ec * 288 + wa1] = s[ec][1];
    }
    __syncthreads();

    // ---- PV phase ----
#pragma unroll
    for (int ec = 0; ec < 4; ++ec) {
        float Av = Vsh[6][ec], Cv = Vsh[7][ec], Pv = Vsh[8][ec];
        float l = 0.f, wr = 0.f, ax = 0.f;
#pragma unroll
        for (int j = 0; j < UB; ++j) {
            float w = W[ec * 288 + row2 + ((j < P) ? j : 0)];
            w = (j < P) ? w : 0.f;
            l += w;
            wr += (j < r) ? w : 0.f;
            ax = fmaf(w, xsr[j], ax);
        }
        float li = 1.f / l;
        float o;
        if (lastp) { float sl = wr * li; o = fmaf(Av, ax * li, fmaf(Cv, sl, Pv * (1.f - sl))); }
        else       o = fmaf(Av, ax * li, Cv);
        ob[rowbase + ec * DMD + tid] = o;
    }
}

// mid-P path (P in {18,21,25,42}): register scheme with masks
template<int UH, int NP>
__device__ __forceinline__ void attn_midA(
    int P, int pn, int r, int Prows,
    const float (*Vsh)[4], const float* xs, const float* U,
    const float* xt, float* __restrict__ ob, int rowbase, int tid)
{
    int lane4 = tid & 3;
    int i0 = tid >> 2;
    int jb = lane4 * UH;

    float Ur[UH], xtr[UH], xq0[UH], xq1[UH];
#pragma unroll
    for (int u = 0; u < UH; ++u) {
        int j = jb + u, jc = (j < P) ? j : 0;
        Ur[u] = U[jc];
        xtr[u] = xt[jc];
        xq0[u] = (j < DMD) ? xs[j] : 0.f;
        int i1x = P + j;
        xq1[u] = (i1x < DMD) ? xs[i1x] : 0.f;
    }
    int nrep = (Prows > 32) ? 2 : 1;
    for (int rep = 0; rep < nrep; ++rep) {
        int i = i0 + rep * 32;
        bool rowact = (i < Prows);
        int ic = rowact ? i : 0;
        float xtic = xt[ic];
        bool rowvalid = (ic < r);
        float g[UH];
#pragma unroll
        for (int u = 0; u < UH; ++u) g[u] = 0.f;
        for (int p = 0; p < pn - 1; ++p) {
            float xi = xs[p * P + ic];
#pragma unroll
            for (int u = 0; u < UH; ++u) {
                int j = jb + u, jc = (j < P) ? j : 0;
                g[u] = fmaf(xi, xs[p * P + jc], g[u]);
            }
        }
        for (int ec = 0; ec < 4; ++ec) {
            float Aq = Vsh[0][ec], Cq = Vsh[1][ec], Pq = Vsh[2][ec];
            float Ak = Vsh[3][ec], Ck = Vsh[4][ec], Pk = Vsh[5][ec];
            float Av = Vsh[6][ec], Cv = Vsh[7][ec], Pv = Vsh[8][ec];
            float c1 = CSC * Aq * Ak, c3 = CSC * Cq * Ak;
            float asi = CSC * (rowvalid ? fmaf(xtic, Aq, Cq) : Pq);

            float l0 = 0.f, l1 = 0.f, w0 = 0.f, w1 = 0.f;
            float accq[NP];
#pragma unroll
            for (int q = 0; q < NP; ++q) accq[q] = 0.f;
#pragma unroll
            for (int u = 0; u < UH; ++u) {
                int j = jb + u;
                float bK = (j < r) ? fmaf(xtr[u], Ak, Ck) : Pk;
                float S = fmaf(asi, bK, fmaf(c3, Ur[u], c1 * g[u]));
                float ev = exp2f(S);
                ev = (j < P) ? ev : 0.f;
                if (u & 1) l1 += ev; else l0 += ev;
                float evr = (j < r) ? ev : 0.f;
                if (u & 1) w1 += evr; else w0 += evr;
                accq[0] = fmaf(ev, xq0[u], accq[0]);
                if (NP >= 2) accq[1] = fmaf(ev, xq1[u], accq[1]);
#pragma unroll
                for (int q = 2; q < NP; ++q) {
                    int idx = q * P + j;
                    float xv = (idx < DMD) ? xs[idx] : 0.f;
                    accq[q] = fmaf(ev, xv, accq[q]);
                }
            }
            float l = l0 + l1, wr = w0 + w1;
            l += __shfl_xor(l, 1);  l += __shfl_xor(l, 2);
            wr += __shfl_xor(wr, 1); wr += __shfl_xor(wr, 2);
#pragma unroll
            for (int q = 0; q < NP; ++q) {
                if (q < pn) {
                    accq[q] += __shfl_xor(accq[q], 1);
                    accq[q] += __shfl_xor(accq[q], 2);
                }
            }
            if (lane4 == 0 && rowact) {
                float li = 1.f / l;
#pragma unroll
                for (int q = 0; q < NP; ++q) {
                    if (q < pn) {
                        int mo = i * pn + q;
                        if (mo < DMD) {
                            float o;
                            if (q == pn - 1) {
                                float sl = wr * li;
                                o = fmaf(Av, accq[q] * li, fmaf(Cv, sl, Pv * (1.f - sl)));
                            } else {
                                o = fmaf(Av, accq[q] * li, Cv);
                            }
                            ob[rowbase + ec * DMD + mo] = o;
                        }
                    }
                }
            }
        }
    }
}

__global__ __launch_bounds__(128) void k_attn(const int* __restrict__ f1p,
                                              const int* __restrict__ f2p,
                                              float* __restrict__ ws,
                                              float* __restrict__ outb) {
    int bn = blockIdx.y;
    int e0 = blockIdx.x * 4;           // 32 chunks of 4 e's
    int br = blockIdx.z;
    int tid = threadIdx.x;

    __shared__ float xs[DMD], U[64], xt[64];
    __shared__ float Vsh[9][4];
    __shared__ float W[4 * 288];

    xs[tid] = ws[WS_XE + bn * DMD + tid];
    if (tid < 36) Vsh[tid >> 2][tid & 3] = ws[WS_VEC + (tid >> 2) * DMD + e0 + (tid & 3)];
    int f = br ? f2p[0] : f1p[0];
    float* ob = br ? outb : (ws + WS_OB);
    const float* Gb = ws + WS_G + (bn * 2 + br) * 288;
    int rowbase = (bn * DMD + e0) * DMD;
    __syncthreads();

    int P = DMD / f;
    int pn = (DMD + P - 1) / P;
    int r = DMD - (pn - 1) * P;
    int Prows = (DMD + pn - 1) / pn;

    if (P == DMD) {
        attn_rank1(Vsh, xs, ob, rowbase, tid);
        return;
    }
    if (tid < P) {
        float s = 0.f;
        for (int p = 0; p < pn - 1; ++p) s += xs[p * P + tid];
        U[tid] = s;
        xt[tid] = (tid < r) ? xs[(pn - 1) * P + tid] : 0.f;
    }
    __syncthreads();

    if (P <= 4)       attn_small<4>(P, pn, r, Prows, Vsh, xs, U, xt, Gb, W, ob, rowbase, tid);
    else if (P <= 8)  attn_small<8>(P, pn, r, Prows, Vsh, xs, U, xt, Gb, W, ob, rowbase, tid);
    else if (P <= 16) attn_small<16>(P, pn, r, Prows, Vsh, xs, U, xt, Gb, W, ob, rowbase, tid);
    else if (P == 64) attn_pow2<64, 2, 2>(Vsh, xs, ob, rowbase, tid);
    else if (P == 32) attn_pow2<32, 4, 4>(Vsh, xs, ob, rowbase, tid);
    else if (P > 32)  attn_midA<16, 4>(P, pn, r, Prows, Vsh, xs, U, xt, ob, rowbase, tid);  // P=42
    else              attn_midA<8, 8>(P, pn, r, Prows, Vsh, xs, U, xt, ob, rowbase, tid);   // 18,21,25
}

// ---------------- out[bn][e][h] = sum_m (pw0*ob0+pw1*ob1)[bn][e][m]*Wo[h][m] + bo[h] ----------
__global__ __launch_bounds__(256) void k_out(const float* __restrict__ Wo,
                                             const float* __restrict__ bo,
                                             const float* __restrict__ ws,
                                             float* __restrict__ out) {
    int blk = blockIdx.x;          // 512 = 128 bn * 4 e-quarters
    int bn = blk >> 2;
    int e0 = (blk & 3) * 32;
    int b = bn >> 6;
    int tid = threadIdx.x;
    __shared__ __align__(16) float WTc[32 * 132];    // [mm][h]
    __shared__ __align__(16) float oT[32][36];       // [mm][e]
    __shared__ float pwsh[2];
    int hg = tid & 31, eg = tid >> 5, h0 = hg * 4;

    // period weights from DFT magnitudes (64-lane reduce, wave 0)
    if (tid < 64) {
        float a0 = ws[WS_AMP + (b * NV + tid) * 2 + 0];
        float a1 = ws[WS_AMP + (b * NV + tid) * 2 + 1];
#pragma unroll
        for (int off = 32; off > 0; off >>= 1) {
            a0 += __shfl_down(a0, off);
            a1 += __shfl_down(a1, off);
        }
        if (tid == 0) {
            a0 *= (1.0f / NV); a1 *= (1.0f / NV);
            float m = fmaxf(a0, a1);
            float e0v = expf(a0 - m), e1v = expf(a1 - m);
            float inv = 1.0f / (e0v + e1v);
            pwsh[0] = e0v * inv;
            pwsh[1] = e1v * inv;
        }
    }
    __syncthreads();
    float pw0 = pwsh[0], pw1 = pwsh[1];

    float acc[4][4];
#pragma unroll
    for (int c = 0; c < 4; ++c)
#pragma unroll
        for (int d = 0; d < 4; ++d) acc[c][d] = 0.f;

    for (int mc = 0; mc < 4; ++mc) {
        int m0 = mc * 32;
        __syncthreads();
        for (int idx = tid; idx < 4096; idx += 256) {
            int h = idx >> 5, mm = idx & 31;
            WTc[mm * 132 + h] = Wo[h * DMD + m0 + mm];
        }
        for (int idx = tid; idx < 1024; idx += 256) {
            int e = idx >> 5, mm = idx & 31;
            int gi = (bn * DMD + e0 + e) * DMD + m0 + mm;
            oT[mm][e] = fmaf(pw0, ws[WS_OB + gi], pw1 * out[gi]);
        }
        __syncthreads();
#pragma unroll 4
        for (int mm = 0; mm < 32; ++mm) {
            const float4 wv = *reinterpret_cast<const float4*>(&WTc[mm * 132 + h0]);
            const float4 q0 = *reinterpret_cast<const float4*>(&oT[mm][eg * 4]);
            float ae[4] = {q0.x, q0.y, q0.z, q0.w};
#pragma unroll
            for (int el = 0; el < 4; ++el) {
                float a = ae[el];
                acc[el][0] = fmaf(a, wv.x, acc[el][0]);
                acc[el][1] = fmaf(a, wv.y, acc[el][1]);
                acc[el][2] = fmaf(a, wv.z, acc[el][2]);
                acc[el][3] = fmaf(a, wv.w, acc[el][3]);
            }
        }
    }
    const float4 bov = *reinterpret_cast<const float4*>(&bo[h0]);
#pragma unroll
    for (int el = 0; el < 4; ++el) {
        float4 res = { acc[el][0] + bov.x, acc[el][1] + bov.y,
                       acc[el][2] + bov.z, acc[el][3] + bov.w };
        int e = e0 + eg * 4 + el;
        *reinterpret_cast<float4*>(&out[(bn * DMD + e) * DMD + h0]) = res;
    }
}

extern "C" void kernel_launch(void* const* d_in, const int* in_sizes, int n_in,
                              void* d_out, int out_size, void* d_ws, size_t ws_size,
                              hipStream_t stream) {
    const float* x       = (const float*)d_in[0];
    const float* W_emb   = (const float*)d_in[1];
    const float* b_emb   = (const float*)d_in[2];
    const float* W_start = (const float*)d_in[3];
    const float* b_start = (const float*)d_in[4];
    const float* Wel     = (const float*)d_in[5];
    const float* bel     = (const float*)d_in[6];
    const float* Wq      = (const float*)d_in[7];
    const float* bq      = (const float*)d_in[8];
    const float* Wk      = (const float*)d_in[9];
    const float* bk      = (const float*)d_in[10];
    const float* Wv      = (const float*)d_in[11];
    const float* bv      = (const float*)d_in[12];
    const float* Wo      = (const float*)d_in[13];
    const float* bo      = (const float*)d_in[14];
    const int*   f1p     = (const int*)d_in[15];
    const int*   f2p     = (const int*)d_in[16];
    float* ws  = (float*)d_ws;
    float* out = (float*)d_out;

    k_xe<<<NBN + 1, 512, 0, stream>>>(x, W_emb, b_emb, f1p, f2p,
                                      Wel, bel, W_start, b_start,
                                      Wq, bq, Wk, bk, Wv, bv, ws);
    k_attn<<<dim3(32, NBN, 2), 128, 0, stream>>>(f1p, f2p, ws, out);
    k_out<<<512, 256, 0, stream>>>(Wo, bo, ws, out);
}